// Round 22
// baseline (164.837 us; speedup 1.0000x reference)
//
#include <hip/hip_runtime.h>
#include <hip/hip_bf16.h>

typedef __bf16 bf16_t;
typedef __attribute__((ext_vector_type(8))) __bf16 bf16x8;
typedef __attribute__((ext_vector_type(4))) float f32x4;
typedef __attribute__((ext_vector_type(8))) int i32x8;
typedef __attribute__((ext_vector_type(4))) int i32x4;

#define NEGV (-1e30f)

// Problem constants
#define BB 4
#define TT 200
#define UU 50
#define U1 51
#define VV 1024
#define DD 512
#define HH 640
#define RTOT (BB*TT*U1)      // 40800
#define NBLK 638
#define SS 101

__device__ __forceinline__ float lae(float a, float b) {
    float mx = fmaxf(a, b);
    return mx + __logf(__expf(a - mx) + __expf(b - mx));
}
__device__ __forceinline__ float lae3(float a, float b, float c) {
    float mx = fmaxf(fmaxf(a, b), c);
    return mx + __logf(__expf(a - mx) + __expf(b - mx) + __expf(c - mx));
}
// cheap tanh for the fp8 build: exp + hw-rcp (1ulp, irrelevant at fp8)
__device__ __forceinline__ float tanh_rcp(float x) {
    x = fminf(fmaxf(x, -10.f), 10.f);
    float ex = __expf(2.f * x);
    float r = __builtin_amdgcn_rcpf(ex + 1.f);
    return (ex - 1.f) * r;
}

// ---- pack W_out into fp8 e4m3 (scaled x16) for the MX K=128 MFMA.
// Layout: [nt(64)][ks(5)][l(64)][32B]; byte m of lane l holds
// k = ks*128 + (l>>4)*32 + m, col v = nt*16 + (l&15).  (A shares k-map.)
__device__ __forceinline__ void pack_out8_mx(const float* __restrict__ W, unsigned* __restrict__ Wf8,
                                             int e32)
{
    int w4   = e32 & 7;          // word within 32B
    int l    = (e32 >> 3) & 63;
    int ksnt = e32 >> 9;
    int ks   = ksnt % 5;
    int nt   = ksnt / 5;
    int v = nt * 16 + (l & 15);
    int kb = ks * 128 + ((l >> 4) << 5) + w4 * 4;
    float f[4];
#pragma unroll
    for (int t = 0; t < 4; ++t) f[t] = W[(size_t)(kb + t) * VV + v] * 16.f;
    unsigned r = __builtin_amdgcn_cvt_pk_fp8_f32(f[0], f[1], 0, false);
    r = __builtin_amdgcn_cvt_pk_fp8_f32(f[2], f[3], r, true);
    Wf8[e32] = r;
}

// bf16 packs, fragment-vectorized: one bf16x8 fragment per thread (16B
// write). Also zeroes out[0]. 40960+51200+65536 = 157696 frags = 616 blocks.
__global__ void pack_bf16(const float* __restrict__ Wenc, const float* __restrict__ Wpred,
                          const float* __restrict__ Wctc,
                          bf16_t* __restrict__ FEnc, bf16_t* __restrict__ FPred,
                          bf16_t* __restrict__ FCtc, float* __restrict__ out)
{
    if (blockIdx.x == 0 && threadIdx.x == 0) out[0] = 0.f;
    int f = blockIdx.x * 256 + threadIdx.x;
    const float* W; bf16_t* Wf; int K32, N;
    if (f < 40960)      { W = Wenc;  Wf = FEnc;  K32 = 16; N = 640; }
    else if (f < 92160) { f -= 40960; W = Wpred; Wf = FPred; K32 = 20; N = 640; }
    else                { f -= 92160; W = Wctc;  Wf = FCtc;  K32 = 16; N = 1024; }
    int l  = f & 63;
    int kk = (f >> 6) % K32;
    int nt = f / (64 * K32);
    int v  = nt * 16 + (l & 15);
    int kb = kk * 32 + ((l >> 4) << 2);
    bf16x8 o;
#pragma unroll
    for (int j = 0; j < 8; ++j) {
        int k = kb + (j & 3) + ((j >> 2) << 4);
        o[j] = (bf16_t)W[(size_t)k * N + v];
    }
    *(bf16x8*)&Wf[(size_t)f * 8] = o;
}

// ---------------- generic bf16 MFMA GEMM (small gemms) ---------------------
template<int K32, int L, bool LSE, int J>
__device__ void gemm_dev(const float* __restrict__ A, int M, int rowbase, int K,
                         const bf16_t* __restrict__ Wf, const float* __restrict__ bias,
                         float* __restrict__ C, float* __restrict__ lse_out, int N,
                         bf16_t* Atile, float (*ps)[8])
{
    const int tid = threadIdx.x;
#pragma unroll
    for (int it = 0; it < J * K32 / 8; ++it) {
        int fi = it * 512 + tid;
        int l = fi & 63, jk = fi >> 6;
        int j = jk / K32, kk = jk - j * K32;
        int row = rowbase + j * 16 + (l & 15);
        if (row > M - 1) row = M - 1;
        int c0 = kk * 32 + ((l >> 4) << 2);
        const float4 a0 = *(const float4*)&A[(size_t)row * K + c0];
        const float4 a1 = *(const float4*)&A[(size_t)row * K + c0 + 16];
        bf16x8 v;
        v[0] = (bf16_t)a0.x; v[1] = (bf16_t)a0.y; v[2] = (bf16_t)a0.z; v[3] = (bf16_t)a0.w;
        v[4] = (bf16_t)a1.x; v[5] = (bf16_t)a1.y; v[6] = (bf16_t)a1.z; v[7] = (bf16_t)a1.w;
        *(bf16x8*)&Atile[(size_t)fi * 8] = v;
    }
    __syncthreads();

    const int l = tid & 63, w = tid >> 6;
    const int lrow = l & 15, lhi = l >> 4;

    f32x4 acc[J][L];
#pragma unroll
    for (int j = 0; j < J; ++j)
#pragma unroll
        for (int li = 0; li < L; ++li) acc[j][li] = f32x4{0.f, 0.f, 0.f, 0.f};

    for (int kk = 0; kk < K32; ++kk) {
        bf16x8 a[J];
#pragma unroll
        for (int j = 0; j < J; ++j)
            a[j] = *(const bf16x8*)&Atile[(size_t)(((j * K32 + kk) * 64 + l) * 8)];
#pragma unroll
        for (int li = 0; li < L; ++li) {
            bf16x8 b = *(const bf16x8*)&Wf[(size_t)(((w * L + li) * K32 + kk) * 64 + l) * 8];
#pragma unroll
            for (int j = 0; j < J; ++j)
                acc[j][li] = __builtin_amdgcn_mfma_f32_16x16x32_bf16(a[j], b, acc[j][li], 0, 0, 0);
        }
    }

    float se[J][4];
    if (LSE) {
#pragma unroll
        for (int j = 0; j < J; ++j)
#pragma unroll
            for (int i = 0; i < 4; ++i) se[j][i] = 0.f;
    }
#pragma unroll
    for (int j = 0; j < J; ++j)
#pragma unroll
        for (int li = 0; li < L; ++li) {
            int col = (w * L + li) * 16 + lrow;
            float bv = bias ? bias[col] : 0.f;
#pragma unroll
            for (int i = 0; i < 4; ++i) {
                int grow = rowbase + 16 * j + lhi * 4 + i;
                float x = acc[j][li][i] + bv;
                if (grow < M) C[(size_t)grow * N + col] = x;
                if (LSE) se[j][i] += __expf(x);
            }
        }
    if (LSE) {
#pragma unroll
        for (int d = 1; d < 16; d <<= 1)
#pragma unroll
            for (int j = 0; j < J; ++j)
#pragma unroll
                for (int i = 0; i < 4; ++i) se[j][i] += __shfl_xor(se[j][i], d);
        if (lrow == 0) {
#pragma unroll
            for (int j = 0; j < J; ++j)
#pragma unroll
                for (int i = 0; i < 4; ++i) ps[16 * j + lhi * 4 + i][w] = se[j][i];
        }
        __syncthreads();
        if (tid < J * 16) {
            float s = 0.f;
#pragma unroll
            for (int w0 = 0; w0 < 8; ++w0) s += ps[tid][w0];
            int grow = rowbase + tid;
            if (grow < M) lse_out[grow] = __logf(s);
        }
    }
}

// blocks 0..49 enc(J=1), 50..56 pred(J=2), 57..106 ctc(J=1),
// 107..426: pack W_out -> fp8 (concurrent on the idle CUs).
__global__ __launch_bounds__(512)
void mfma_gemm3(const float* __restrict__ x_enc, const float* __restrict__ x_dec,
                const bf16_t* __restrict__ FEnc, const bf16_t* __restrict__ FPred,
                const bf16_t* __restrict__ FCtc, const float* __restrict__ b_ctc,
                float* __restrict__ enc_proj, float* __restrict__ pred_proj,
                float* __restrict__ ctc_logits, float* __restrict__ ctc_lse,
                const float* __restrict__ Wout, unsigned* __restrict__ FOut8)
{
    __shared__ bf16_t Atile[2560 * 8];   // J=2,K32=20 max: 2560 frags
    __shared__ float ps[64][8];
    int blk = blockIdx.x;
    if (blk >= 107) {
        int e = (blk - 107) * 512 + threadIdx.x;   // 163840 u32 total
        pack_out8_mx(Wout, FOut8, e);
        return;
    }
    if (blk < 50)
        gemm_dev<16, 5, false, 1>(x_enc, 800, blk * 16, 512, FEnc, nullptr, enc_proj, nullptr, 640, Atile, ps);
    else if (blk < 57)
        gemm_dev<20, 5, false, 2>(x_dec, 204, (blk - 50) * 32, 640, FPred, nullptr, pred_proj, nullptr, 640, Atile, ps);
    else
        gemm_dev<16, 8, true, 1>(x_enc, 800, (blk - 57) * 16, 512, FCtc, b_ctc, ctc_logits, ctc_lse, 1024, Atile, ps);
}

// ---------------- fused build + MX-fp8 K=128 GEMM + row-LSE + gather -------
// blocks 0..637: joint tile (R20 structure); blocks 638..641: CTC DP (rides
// concurrently — depends only on gemm3 outputs, no sibling-block deps).
__global__ __launch_bounds__(512)
void joint_gemm(const float* __restrict__ enc,   // (800,640)
                const float* __restrict__ pred,  // (204,640)
                const float* __restrict__ bj,    // (640)
                const unsigned* __restrict__ Wf8,// packed fp8 (x16 scale)
                const float* __restrict__ bo,    // (1024)
                const int* __restrict__ target,  // (4,50)
                float* __restrict__ blank_buf, float* __restrict__ emit_buf,
                const float* __restrict__ ctc_logits, const float* __restrict__ ctc_lse,
                const int* __restrict__ frame_len, const int* __restrict__ tgt_len,
                float* __restrict__ out)
{
    __shared__ __align__(16) char smem[84992];       // tile 41984 | Afrag 40960
    __shared__ const float* ep[64];
    __shared__ const float* pp[64];
    const int tid = threadIdx.x;
    const int blk = blockIdx.x;

    if (blk >= NBLK) {
        // ---- CTC DP: 2 states per lane, branchless 8-step unroll ----
        const int b = blk - NBLK;
        float* lpE = (float*)smem;                   // [208]
        float* lpO = (float*)smem + 208;             // [50][209]
        for (int i = tid; i < TT; i += 512) {
            int bt = b * TT + i;
            lpE[i] = ctc_logits[(size_t)bt * VV + (VV - 1)] - ctc_lse[bt];
        }
        for (int i = tid; i < TT * UU; i += 512) {
            int t = i / UU, uu = i - t * UU;
            int bt = b * TT + t;
            lpO[uu * 209 + t] = ctc_logits[(size_t)bt * VV + target[b * UU + uu]] - ctc_lse[bt];
        }
        __syncthreads();
        if (tid >= 64) return;
        const int u = tid;
        const int fl = frame_len[b], tl = tgt_len[b];
        const bool acte = (u <= 50);
        const bool acto = (u < 50);
        bool skip = (u >= 1 && u < UU) ? (target[b * UU + u] != target[b * UU + u - 1]) : false;
        const float* orow = lpO + u * 209;
        float old_e = (u == 0) ? lpE[0] : NEGV;
        float old_o = (u == 0) ? orow[0] : NEGV;
        float Esave = (fl == 1) ? old_e : NEGV;
        float Osave = (fl == 1) ? old_o : NEGV;

        for (int t0 = 1; t0 <= 193; t0 += 8) {
            float bo8[8], be8[8];
#pragma unroll
            for (int s = 0; s < 8; ++s) { bo8[s] = orow[t0 + s]; be8[s] = lpE[t0 + s]; }
#pragma unroll
            for (int s = 0; s < 8; ++s) {
                int t = t0 + s;
                float prev_o = __shfl_up(old_o, 1);
                if (u == 0) prev_o = NEGV;
                float ne = be8[s] + lae(old_e, prev_o);
                float no = bo8[s] + lae3(old_o, old_e, skip ? prev_o : NEGV);
                old_e = acte ? ne : NEGV;
                old_o = acto ? no : NEGV;
                bool hv = (t == fl - 1) && (t < TT);
                Esave = hv ? old_e : Esave;
                Osave = hv ? old_o : Osave;
            }
        }
        float a_last = __shfl(Esave, tl);
        float a_prev = __shfl(Osave, tl - 1);
        if (u == 0) atomicAdd(out, -0.075f * lae(a_last, a_prev));
        return;
    }

    char* tile = smem;                    // P1 output [64][656B]
    char* Afrag8 = smem + 41984;          // fragment-order A (40960B)
    const int l = tid & 63, w = tid >> 6;
    const int lrow = l & 15, lhi = l >> 4;

    if (tid < 64) {
        int r = blk * 64 + tid; if (r > RTOT - 1) r = RTOT - 1;
        int b = r / (TT * U1); int rem = r - b * (TT * U1);
        int t = rem / U1;      int u = rem - t * U1;
        ep[tid] = enc + (size_t)(b * TT + t) * HH;
        pp[tid] = pred + (size_t)(b * U1 + u) * HH;
    }
    __syncthreads();

    // P1: row-major coalesced compute -> tile
#pragma unroll 4
    for (int it = 0; it < 20; ++it) {
        int i = it * 512 + tid;        // 0..10239
        int row = i / 160;
        int c4 = i - row * 160;
        int c0 = c4 * 4;
        const float4 e4 = *(const float4*)&ep[row][c0];
        const float4 p4 = *(const float4*)&pp[row][c0];
        const float4 q4 = *(const float4*)&bj[c0];
        float f0 = tanh_rcp(e4.x + p4.x + q4.x);
        float f1 = tanh_rcp(e4.y + p4.y + q4.y);
        float f2 = tanh_rcp(e4.z + p4.z + q4.z);
        float f3 = tanh_rcp(e4.w + p4.w + q4.w);
        unsigned r0 = __builtin_amdgcn_cvt_pk_fp8_f32(f0, f1, 0, false);
        unsigned v = __builtin_amdgcn_cvt_pk_fp8_f32(f2, f3, r0, true);
        *(unsigned*)&tile[row * 656 + c0] = v;
    }
    __syncthreads();

    // P2: direct LDS->LDS fragment reorder (no cross-barrier registers).
#pragma unroll
    for (int it = 0; it < 5; ++it) {
        int c = it * 512 + tid;        // 0..2559
        int lA = c & 63;
        int plane = c >> 6;            // 0..39
        int h = plane & 1;
        int jks = plane >> 1;
        int ks = jks % 5;
        int j = jks / 5;
        int row = j * 16 + (lA & 15);
        int kbase = ks * 128 + ((lA >> 4) << 5) + h * 16;
        uint4 v = *(const uint4*)&tile[row * 656 + kbase];
        *(uint4*)&Afrag8[(size_t)c * 16] = v;
    }
    __syncthreads();

    f32x4 acc[4][8];
#pragma unroll
    for (int j = 0; j < 4; ++j)
#pragma unroll
        for (int li = 0; li < 8; ++li) acc[j][li] = f32x4{0.f, 0.f, 0.f, 0.f};

    const char* Bp8 = (const char*)Wf8 + (size_t)(w * 8) * 10240 + (size_t)l * 32;

    const int rot = blk % 5;
    auto kstep = [&](int ks) {
        i32x8 a[4];
#pragma unroll
        for (int j = 0; j < 4; ++j) {
            i32x4 lo = *(const i32x4*)(Afrag8 + (size_t)(((j * 5 + ks) * 2 + 0) * 1024 + l * 16));
            i32x4 hi = *(const i32x4*)(Afrag8 + (size_t)(((j * 5 + ks) * 2 + 1) * 1024 + l * 16));
            a[j][0] = lo[0]; a[j][1] = lo[1]; a[j][2] = lo[2]; a[j][3] = lo[3];
            a[j][4] = hi[0]; a[j][5] = hi[1]; a[j][6] = hi[2]; a[j][7] = hi[3];
        }
#pragma unroll
        for (int li = 0; li < 8; ++li) {
            i32x8 b = *(const i32x8*)(Bp8 + (size_t)li * 10240 + (size_t)ks * 2048);
#pragma unroll
            for (int j = 0; j < 4; ++j)
                acc[j][li] = __builtin_amdgcn_mfma_scale_f32_16x16x128_f8f6f4(
                    a[j], b, acc[j][li], 0, 0,
                    0, 0x7F7F7F7F, 0, 0x7F7F7F7F);   // scales = 1.0 (e8m0 127)
        }
    };
    for (int ks0 = rot; ks0 < 5; ++ks0) kstep(ks0);
    for (int ks0 = 0; ks0 < rot; ++ks0) kstep(ks0);

    // per-thread target tokens for the 16 owned rows
    int tg[4][4];
#pragma unroll
    for (int j = 0; j < 4; ++j)
#pragma unroll
        for (int i = 0; i < 4; ++i) {
            int r = blk * 64 + 16 * j + lhi * 4 + i; if (r > RTOT - 1) r = RTOT - 1;
            int b = r / (TT * U1); int rem = r - b * (TT * U1);
            int u = rem % U1;
            tg[j][i] = (u < UU) ? target[b * UU + u] : -1;
        }

    float se[4][4], ee[4][4], bbv[4][4];
#pragma unroll
    for (int j = 0; j < 4; ++j)
#pragma unroll
        for (int i = 0; i < 4; ++i) { se[j][i] = 0.f; ee[j][i] = NEGV; bbv[j][i] = NEGV; }

#pragma unroll
    for (int li = 0; li < 8; ++li) {
        int col = (w * 8 + li) * 16 + lrow;
        float bv = bo[col];
#pragma unroll
        for (int j = 0; j < 4; ++j)
#pragma unroll
            for (int i = 0; i < 4; ++i) {
                float x = acc[j][li][i] * 0.0625f + bv;   // undo x16 W scale
                se[j][i] += __expf(x);
                if (col == tg[j][i]) ee[j][i] = x;
            }
    }
    // blank col 1023 lives only at w==7, li==7, lrow==15 (uniform guard)
    if (w == 7) {
        float bv = bo[1023];
#pragma unroll
        for (int j = 0; j < 4; ++j)
#pragma unroll
            for (int i = 0; i < 4; ++i) {
                float x = acc[j][7][i] * 0.0625f + bv;
                if (lrow == 15) bbv[j][i] = x;
            }
    }
#pragma unroll
    for (int d = 1; d < 16; d <<= 1)
#pragma unroll
        for (int j = 0; j < 4; ++j)
#pragma unroll
            for (int i = 0; i < 4; ++i) {
                se[j][i] += __shfl_xor(se[j][i], d);
                ee[j][i] = fmaxf(ee[j][i], __shfl_xor(ee[j][i], d));
                bbv[j][i] = fmaxf(bbv[j][i], __shfl_xor(bbv[j][i], d));
            }

    // Afrag8 dead; overlay cross-wave reduction arrays [64][8].
    __syncthreads();
    float (*ps)[8] = (float (*)[8])(Afrag8);
    float (*pe)[8] = (float (*)[8])(Afrag8 + 2048);
    float (*pb)[8] = (float (*)[8])(Afrag8 + 4096);
    if (lrow == 0) {
#pragma unroll
        for (int j = 0; j < 4; ++j)
#pragma unroll
            for (int i = 0; i < 4; ++i) {
                int r = 16 * j + lhi * 4 + i;
                ps[r][w] = se[j][i]; pe[r][w] = ee[j][i]; pb[r][w] = bbv[j][i];
            }
    }
    __syncthreads();
    if (tid < 64) {
        float s = 0.f, e = NEGV, bq = NEGV;
#pragma unroll
        for (int w0 = 0; w0 < 8; ++w0) {
            s += ps[tid][w0];
            e = fmaxf(e, pe[tid][w0]);
            bq = fmaxf(bq, pb[tid][w0]);
        }
        float lse = __logf(s);
        int gid = blk * 64 + tid;
        if (gid < RTOT) {
            blank_buf[gid] = bq - lse;
            emit_buf[gid]  = e - lse;
        }
    }
}

// ---------------- RNNT DP (anti-diagonal wavefront) + combine --------------
__global__ __launch_bounds__(256)
void dp_rnnt(const float* __restrict__ blank_buf, const float* __restrict__ emit_buf,
             const int* __restrict__ frame_len, const int* __restrict__ tgt_len,
             float* __restrict__ out)
{
    __shared__ __align__(16) float sm[28416];   // pk[64][217] float2
    const int b = blockIdx.x;
    const int tid = threadIdx.x;

    float2* pk = (float2*)sm;               // [64][217]; t stored at t+8
    for (int i = tid; i < TT * U1; i += 256) {
        int t = i / U1, uu = i - t * U1;
        float bl = blank_buf[(b * TT + t) * U1 + uu];
        float em = emit_buf[(b * TT + t) * U1 + uu];
        pk[uu * 217 + t + 8] = make_float2(bl, em);
    }
    __syncthreads();
    if (tid >= 64) return;
    const int u = tid;
    const int fl = frame_len[b], tl = tgt_len[b];
    const int dh = fl - 1 + tl;             // harvest diagonal
    const bool isTL = (u == tl);
    const bool act = (u < U1);
    float A = (u == 0) ? 0.f : NEGV;
    float Asave = (dh == 0 && isTL) ? A : NEGV;
    const float2* prow = pk + u * 217;

    for (int d0 = 1; d0 <= 249; d0 += 8) {
        int tb = d0 - 1 - u;
        int tc = tb; if (tc < -8) tc = -8; if (tc > 200) tc = 200;
        float2 buf[8];
#pragma unroll
        for (int s = 0; s < 8; ++s) buf[s] = prow[tc + 8 + s];
#pragma unroll
        for (int s = 0; s < 8; ++s) {
            int d = d0 + s;
            int t_new = d - u;
            float2 be = buf[s];
            float vshare = A + be.y;
            float left = __shfl_up(vshare, 1);
            if (u == 0) left = NEGV;
            float up = (t_new >= 1) ? (A + be.x) : NEGV;
            float Anew = lae(up, left);
            bool valid = act && (t_new >= 0) && (t_new < TT);
            A = valid ? Anew : A;
            Asave = (isTL && d == dh) ? A : Asave;
        }
    }
    if (isTL && act) {
        float bl = prow[(fl - 1) + 8].x;
        atomicAdd(out, -0.25f * (Asave + bl));
    }
}

extern "C" void kernel_launch(void* const* d_in, const int* in_sizes, int n_in,
                              void* d_out, int out_size, void* d_ws, size_t ws_size,
                              hipStream_t stream)
{
    const float* x_enc   = (const float*)d_in[0];
    const float* x_dec   = (const float*)d_in[1];
    const int*   target  = (const int*)d_in[2];
    const int*   frame_l = (const int*)d_in[3];
    const int*   tgt_l   = (const int*)d_in[4];
    const float* W_ctc   = (const float*)d_in[5];
    const float* b_ctc   = (const float*)d_in[6];
    const float* W_enc   = (const float*)d_in[7];
    const float* W_pred  = (const float*)d_in[8];
    const float* b_joint = (const float*)d_in[9];
    const float* W_out   = (const float*)d_in[10];
    const float* b_out   = (const float*)d_in[11];
    float* out = (float*)d_out;

    float* wsf        = (float*)d_ws;
    float* enc_proj   = wsf;                       // 512000
    float* pred_proj  = wsf + 512000;              // 130560
    float* ctc_logits = wsf + 642560;              // 819200
    float* ctc_lse    = wsf + 1461760;             // 832
    float* blank_buf  = wsf + 1462592;             // 40832
    float* emit_buf   = wsf + 1503424;             // 40832 (+pad to 1544272)
    unsigned* FOut8 = (unsigned*)(wsf + 1544272);  // 163840 u32 (655360 B fp8)
    bf16_t* FEnc  = (bf16_t*)(wsf + 1708112);      // 327680 bf16
    bf16_t* FPred = (bf16_t*)(wsf + 1871952);      // 409600 bf16
    bf16_t* FCtc  = (bf16_t*)(wsf + 2076752);      // 524288 bf16

    pack_bf16<<<616, 256, 0, stream>>>(W_enc, W_pred, W_ctc, FEnc, FPred, FCtc, out);
    mfma_gemm3<<<427, 512, 0, stream>>>(x_enc, x_dec, FEnc, FPred, FCtc, b_ctc,
                                        enc_proj, pred_proj, ctc_logits, ctc_lse,
                                        W_out, FOut8);
    joint_gemm<<<NBLK + 4, 512, 0, stream>>>(enc_proj, pred_proj, b_joint, FOut8, b_out,
                                             target, blank_buf, emit_buf,
                                             ctc_logits, ctc_lse, frame_l, tgt_l, out);
    dp_rnnt<<<4, 256, 0, stream>>>(blank_buf, emit_buf, frame_l, tgt_l, out);
}

// Round 23
// 148.577 us; speedup vs baseline: 1.1094x; 1.1094x over previous
//
#include <hip/hip_runtime.h>
#include <hip/hip_bf16.h>

typedef __bf16 bf16_t;
typedef __attribute__((ext_vector_type(8))) __bf16 bf16x8;
typedef __attribute__((ext_vector_type(4))) float f32x4;
typedef __attribute__((ext_vector_type(8))) int i32x8;
typedef __attribute__((ext_vector_type(4))) int i32x4;

#define NEGV (-1e30f)

// Problem constants
#define BB 4
#define TT 200
#define UU 50
#define U1 51
#define VV 1024
#define DD 512
#define HH 640
#define RTOT (BB*TT*U1)      // 40800
#define NBLK 638
#define SS 101

__device__ __forceinline__ float lae(float a, float b) {
    float mx = fmaxf(a, b);
    return mx + __logf(__expf(a - mx) + __expf(b - mx));
}
__device__ __forceinline__ float lae3(float a, float b, float c) {
    float mx = fmaxf(fmaxf(a, b), c);
    return mx + __logf(__expf(a - mx) + __expf(b - mx) + __expf(c - mx));
}
// cheap tanh for the fp8 build: exp + hw-rcp (1ulp, irrelevant at fp8)
__device__ __forceinline__ float tanh_rcp(float x) {
    x = fminf(fmaxf(x, -10.f), 10.f);
    float ex = __expf(2.f * x);
    float r = __builtin_amdgcn_rcpf(ex + 1.f);
    return (ex - 1.f) * r;
}

// ---- pack W_out into fp8 e4m3 (scaled x16) for the MX K=128 MFMA.
// Layout: [nt(64)][ks(5)][l(64)][32B]; byte m of lane l holds
// k = ks*128 + (l>>4)*32 + m, col v = nt*16 + (l&15).  (A shares k-map.)
__device__ __forceinline__ void pack_out8_mx(const float* __restrict__ W, unsigned* __restrict__ Wf8,
                                             int e32)
{
    int w4   = e32 & 7;          // word within 32B
    int l    = (e32 >> 3) & 63;
    int ksnt = e32 >> 9;
    int ks   = ksnt % 5;
    int nt   = ksnt / 5;
    int v = nt * 16 + (l & 15);
    int kb = ks * 128 + ((l >> 4) << 5) + w4 * 4;
    float f[4];
#pragma unroll
    for (int t = 0; t < 4; ++t) f[t] = W[(size_t)(kb + t) * VV + v] * 16.f;
    unsigned r = __builtin_amdgcn_cvt_pk_fp8_f32(f[0], f[1], 0, false);
    r = __builtin_amdgcn_cvt_pk_fp8_f32(f[2], f[3], r, true);
    Wf8[e32] = r;
}

// bf16 packs, fragment-vectorized: one bf16x8 fragment per thread (16B
// write). Also zeroes out[0]. 40960+51200+65536 = 157696 frags = 616 blocks.
__global__ void pack_bf16(const float* __restrict__ Wenc, const float* __restrict__ Wpred,
                          const float* __restrict__ Wctc,
                          bf16_t* __restrict__ FEnc, bf16_t* __restrict__ FPred,
                          bf16_t* __restrict__ FCtc, float* __restrict__ out)
{
    if (blockIdx.x == 0 && threadIdx.x == 0) out[0] = 0.f;
    int f = blockIdx.x * 256 + threadIdx.x;
    const float* W; bf16_t* Wf; int K32, N;
    if (f < 40960)      { W = Wenc;  Wf = FEnc;  K32 = 16; N = 640; }
    else if (f < 92160) { f -= 40960; W = Wpred; Wf = FPred; K32 = 20; N = 640; }
    else                { f -= 92160; W = Wctc;  Wf = FCtc;  K32 = 16; N = 1024; }
    int l  = f & 63;
    int kk = (f >> 6) % K32;
    int nt = f / (64 * K32);
    int v  = nt * 16 + (l & 15);
    int kb = kk * 32 + ((l >> 4) << 2);
    bf16x8 o;
#pragma unroll
    for (int j = 0; j < 8; ++j) {
        int k = kb + (j & 3) + ((j >> 2) << 4);
        o[j] = (bf16_t)W[(size_t)k * N + v];
    }
    *(bf16x8*)&Wf[(size_t)f * 8] = o;
}

// ---------------- generic bf16 MFMA GEMM (small gemms) ---------------------
template<int K32, int L, bool LSE, int J>
__device__ void gemm_dev(const float* __restrict__ A, int M, int rowbase, int K,
                         const bf16_t* __restrict__ Wf, const float* __restrict__ bias,
                         float* __restrict__ C, float* __restrict__ lse_out, int N,
                         bf16_t* Atile, float (*ps)[8])
{
    const int tid = threadIdx.x;
#pragma unroll
    for (int it = 0; it < J * K32 / 8; ++it) {
        int fi = it * 512 + tid;
        int l = fi & 63, jk = fi >> 6;
        int j = jk / K32, kk = jk - j * K32;
        int row = rowbase + j * 16 + (l & 15);
        if (row > M - 1) row = M - 1;
        int c0 = kk * 32 + ((l >> 4) << 2);
        const float4 a0 = *(const float4*)&A[(size_t)row * K + c0];
        const float4 a1 = *(const float4*)&A[(size_t)row * K + c0 + 16];
        bf16x8 v;
        v[0] = (bf16_t)a0.x; v[1] = (bf16_t)a0.y; v[2] = (bf16_t)a0.z; v[3] = (bf16_t)a0.w;
        v[4] = (bf16_t)a1.x; v[5] = (bf16_t)a1.y; v[6] = (bf16_t)a1.z; v[7] = (bf16_t)a1.w;
        *(bf16x8*)&Atile[(size_t)fi * 8] = v;
    }
    __syncthreads();

    const int l = tid & 63, w = tid >> 6;
    const int lrow = l & 15, lhi = l >> 4;

    f32x4 acc[J][L];
#pragma unroll
    for (int j = 0; j < J; ++j)
#pragma unroll
        for (int li = 0; li < L; ++li) acc[j][li] = f32x4{0.f, 0.f, 0.f, 0.f};

    for (int kk = 0; kk < K32; ++kk) {
        bf16x8 a[J];
#pragma unroll
        for (int j = 0; j < J; ++j)
            a[j] = *(const bf16x8*)&Atile[(size_t)(((j * K32 + kk) * 64 + l) * 8)];
#pragma unroll
        for (int li = 0; li < L; ++li) {
            bf16x8 b = *(const bf16x8*)&Wf[(size_t)(((w * L + li) * K32 + kk) * 64 + l) * 8];
#pragma unroll
            for (int j = 0; j < J; ++j)
                acc[j][li] = __builtin_amdgcn_mfma_f32_16x16x32_bf16(a[j], b, acc[j][li], 0, 0, 0);
        }
    }

    float se[J][4];
    if (LSE) {
#pragma unroll
        for (int j = 0; j < J; ++j)
#pragma unroll
            for (int i = 0; i < 4; ++i) se[j][i] = 0.f;
    }
#pragma unroll
    for (int j = 0; j < J; ++j)
#pragma unroll
        for (int li = 0; li < L; ++li) {
            int col = (w * L + li) * 16 + lrow;
            float bv = bias ? bias[col] : 0.f;
#pragma unroll
            for (int i = 0; i < 4; ++i) {
                int grow = rowbase + 16 * j + lhi * 4 + i;
                float x = acc[j][li][i] + bv;
                if (grow < M) C[(size_t)grow * N + col] = x;
                if (LSE) se[j][i] += __expf(x);
            }
        }
    if (LSE) {
#pragma unroll
        for (int d = 1; d < 16; d <<= 1)
#pragma unroll
            for (int j = 0; j < J; ++j)
#pragma unroll
                for (int i = 0; i < 4; ++i) se[j][i] += __shfl_xor(se[j][i], d);
        if (lrow == 0) {
#pragma unroll
            for (int j = 0; j < J; ++j)
#pragma unroll
                for (int i = 0; i < 4; ++i) ps[16 * j + lhi * 4 + i][w] = se[j][i];
        }
        __syncthreads();
        if (tid < J * 16) {
            float s = 0.f;
#pragma unroll
            for (int w0 = 0; w0 < 8; ++w0) s += ps[tid][w0];
            int grow = rowbase + tid;
            if (grow < M) lse_out[grow] = __logf(s);
        }
    }
}

// blocks 0..49 enc(J=1), 50..56 pred(J=2), 57..106 ctc(J=1),
// 107..426: pack W_out -> fp8 (concurrent on the idle CUs).
__global__ __launch_bounds__(512)
void mfma_gemm3(const float* __restrict__ x_enc, const float* __restrict__ x_dec,
                const bf16_t* __restrict__ FEnc, const bf16_t* __restrict__ FPred,
                const bf16_t* __restrict__ FCtc, const float* __restrict__ b_ctc,
                float* __restrict__ enc_proj, float* __restrict__ pred_proj,
                float* __restrict__ ctc_logits, float* __restrict__ ctc_lse,
                const float* __restrict__ Wout, unsigned* __restrict__ FOut8)
{
    __shared__ bf16_t Atile[2560 * 8];   // J=2,K32=20 max: 2560 frags
    __shared__ float ps[64][8];
    int blk = blockIdx.x;
    if (blk >= 107) {
        int e = (blk - 107) * 512 + threadIdx.x;   // 163840 u32 total
        pack_out8_mx(Wout, FOut8, e);
        return;
    }
    if (blk < 50)
        gemm_dev<16, 5, false, 1>(x_enc, 800, blk * 16, 512, FEnc, nullptr, enc_proj, nullptr, 640, Atile, ps);
    else if (blk < 57)
        gemm_dev<20, 5, false, 2>(x_dec, 204, (blk - 50) * 32, 640, FPred, nullptr, pred_proj, nullptr, 640, Atile, ps);
    else
        gemm_dev<16, 8, true, 1>(x_enc, 800, (blk - 57) * 16, 512, FCtc, b_ctc, ctc_logits, ctc_lse, 1024, Atile, ps);
}

// ---------------- fused build + MX-fp8 K=128 GEMM + row-LSE + gather -------
// blocks 0..3: CTC DP (FIRST so they start in the first scheduling wave and
// hide under the joint span); blocks 4..641: joint tiles (jb = blk-4).
__global__ __launch_bounds__(512)
void joint_gemm(const float* __restrict__ enc,   // (800,640)
                const float* __restrict__ pred,  // (204,640)
                const float* __restrict__ bj,    // (640)
                const unsigned* __restrict__ Wf8,// packed fp8 (x16 scale)
                const float* __restrict__ bo,    // (1024)
                const int* __restrict__ target,  // (4,50)
                float* __restrict__ blank_buf, float* __restrict__ emit_buf,
                const float* __restrict__ ctc_logits, const float* __restrict__ ctc_lse,
                const int* __restrict__ frame_len, const int* __restrict__ tgt_len,
                float* __restrict__ out)
{
    __shared__ __align__(16) char smem[82944];       // tile 41984 | Afrag 40960
    __shared__ const float* ep[64];
    __shared__ const float* pp[64];
    const int tid = threadIdx.x;
    const int blk = blockIdx.x;

    if (blk < 4) {
        // ---- CTC DP: 2 states per lane, branchless 8-step unroll ----
        const int b = blk;
        float* lpE = (float*)smem;                   // [208]
        float* lpO = (float*)smem + 208;             // [50][209]
        for (int i = tid; i < TT; i += 512) {
            int bt = b * TT + i;
            lpE[i] = ctc_logits[(size_t)bt * VV + (VV - 1)] - ctc_lse[bt];
        }
        for (int i = tid; i < TT * UU; i += 512) {
            int t = i / UU, uu = i - t * UU;
            int bt = b * TT + t;
            lpO[uu * 209 + t] = ctc_logits[(size_t)bt * VV + target[b * UU + uu]] - ctc_lse[bt];
        }
        __syncthreads();
        if (tid >= 64) return;
        const int u = tid;
        const int fl = frame_len[b], tl = tgt_len[b];
        const bool acte = (u <= 50);
        const bool acto = (u < 50);
        bool skip = (u >= 1 && u < UU) ? (target[b * UU + u] != target[b * UU + u - 1]) : false;
        const float* orow = lpO + u * 209;
        float old_e = (u == 0) ? lpE[0] : NEGV;
        float old_o = (u == 0) ? orow[0] : NEGV;
        float Esave = (fl == 1) ? old_e : NEGV;
        float Osave = (fl == 1) ? old_o : NEGV;

        for (int t0 = 1; t0 <= 193; t0 += 8) {
            float bo8[8], be8[8];
#pragma unroll
            for (int s = 0; s < 8; ++s) { bo8[s] = orow[t0 + s]; be8[s] = lpE[t0 + s]; }
#pragma unroll
            for (int s = 0; s < 8; ++s) {
                int t = t0 + s;
                float prev_o = __shfl_up(old_o, 1);
                if (u == 0) prev_o = NEGV;
                float ne = be8[s] + lae(old_e, prev_o);
                float no = bo8[s] + lae3(old_o, old_e, skip ? prev_o : NEGV);
                old_e = acte ? ne : NEGV;
                old_o = acto ? no : NEGV;
                bool hv = (t == fl - 1) && (t < TT);
                Esave = hv ? old_e : Esave;
                Osave = hv ? old_o : Osave;
            }
        }
        float a_last = __shfl(Esave, tl);
        float a_prev = __shfl(Osave, tl - 1);
        if (u == 0) atomicAdd(out, -0.075f * lae(a_last, a_prev));
        return;
    }

    const int jb = blk - 4;               // joint row-tile index 0..637
    char* tile = smem;                    // P1 output [64][656B]
    char* Afrag8 = smem + 41984;          // fragment-order A (40960B)
    const int l = tid & 63, w = tid >> 6;
    const int lrow = l & 15, lhi = l >> 4;

    if (tid < 64) {
        int r = jb * 64 + tid; if (r > RTOT - 1) r = RTOT - 1;
        int b = r / (TT * U1); int rem = r - b * (TT * U1);
        int t = rem / U1;      int u = rem - t * U1;
        ep[tid] = enc + (size_t)(b * TT + t) * HH;
        pp[tid] = pred + (size_t)(b * U1 + u) * HH;
    }
    __syncthreads();

    // P1: row-major coalesced compute -> tile
#pragma unroll 4
    for (int it = 0; it < 20; ++it) {
        int i = it * 512 + tid;        // 0..10239
        int row = i / 160;
        int c4 = i - row * 160;
        int c0 = c4 * 4;
        const float4 e4 = *(const float4*)&ep[row][c0];
        const float4 p4 = *(const float4*)&pp[row][c0];
        const float4 q4 = *(const float4*)&bj[c0];
        float f0 = tanh_rcp(e4.x + p4.x + q4.x);
        float f1 = tanh_rcp(e4.y + p4.y + q4.y);
        float f2 = tanh_rcp(e4.z + p4.z + q4.z);
        float f3 = tanh_rcp(e4.w + p4.w + q4.w);
        unsigned r0 = __builtin_amdgcn_cvt_pk_fp8_f32(f0, f1, 0, false);
        unsigned v = __builtin_amdgcn_cvt_pk_fp8_f32(f2, f3, r0, true);
        *(unsigned*)&tile[row * 656 + c0] = v;
    }
    __syncthreads();

    // P2: direct LDS->LDS fragment reorder (no cross-barrier registers).
#pragma unroll
    for (int it = 0; it < 5; ++it) {
        int c = it * 512 + tid;        // 0..2559
        int lA = c & 63;
        int plane = c >> 6;            // 0..39
        int h = plane & 1;
        int jks = plane >> 1;
        int ks = jks % 5;
        int j = jks / 5;
        int row = j * 16 + (lA & 15);
        int kbase = ks * 128 + ((lA >> 4) << 5) + h * 16;
        uint4 v = *(const uint4*)&tile[row * 656 + kbase];
        *(uint4*)&Afrag8[(size_t)c * 16] = v;
    }
    __syncthreads();

    f32x4 acc[4][8];
#pragma unroll
    for (int j = 0; j < 4; ++j)
#pragma unroll
        for (int li = 0; li < 8; ++li) acc[j][li] = f32x4{0.f, 0.f, 0.f, 0.f};

    const char* Bp8 = (const char*)Wf8 + (size_t)(w * 8) * 10240 + (size_t)l * 32;

    const int rot = jb % 5;
    auto kstep = [&](int ks) {
        i32x8 a[4];
#pragma unroll
        for (int j = 0; j < 4; ++j) {
            i32x4 lo = *(const i32x4*)(Afrag8 + (size_t)(((j * 5 + ks) * 2 + 0) * 1024 + l * 16));
            i32x4 hi = *(const i32x4*)(Afrag8 + (size_t)(((j * 5 + ks) * 2 + 1) * 1024 + l * 16));
            a[j][0] = lo[0]; a[j][1] = lo[1]; a[j][2] = lo[2]; a[j][3] = lo[3];
            a[j][4] = hi[0]; a[j][5] = hi[1]; a[j][6] = hi[2]; a[j][7] = hi[3];
        }
#pragma unroll
        for (int li = 0; li < 8; ++li) {
            i32x8 b = *(const i32x8*)(Bp8 + (size_t)li * 10240 + (size_t)ks * 2048);
#pragma unroll
            for (int j = 0; j < 4; ++j)
                acc[j][li] = __builtin_amdgcn_mfma_scale_f32_16x16x128_f8f6f4(
                    a[j], b, acc[j][li], 0, 0,
                    0, 0x7F7F7F7F, 0, 0x7F7F7F7F);   // scales = 1.0 (e8m0 127)
        }
    };
    for (int ks0 = rot; ks0 < 5; ++ks0) kstep(ks0);
    for (int ks0 = 0; ks0 < rot; ++ks0) kstep(ks0);

    // per-thread target tokens for the 16 owned rows
    int tg[4][4];
#pragma unroll
    for (int j = 0; j < 4; ++j)
#pragma unroll
        for (int i = 0; i < 4; ++i) {
            int r = jb * 64 + 16 * j + lhi * 4 + i; if (r > RTOT - 1) r = RTOT - 1;
            int b = r / (TT * U1); int rem = r - b * (TT * U1);
            int u = rem % U1;
            tg[j][i] = (u < UU) ? target[b * UU + u] : -1;
        }

    float se[4][4], ee[4][4], bbv[4][4];
#pragma unroll
    for (int j = 0; j < 4; ++j)
#pragma unroll
        for (int i = 0; i < 4; ++i) { se[j][i] = 0.f; ee[j][i] = NEGV; bbv[j][i] = NEGV; }

#pragma unroll
    for (int li = 0; li < 8; ++li) {
        int col = (w * 8 + li) * 16 + lrow;
        float bv = bo[col];
#pragma unroll
        for (int j = 0; j < 4; ++j)
#pragma unroll
            for (int i = 0; i < 4; ++i) {
                float x = acc[j][li][i] * 0.0625f + bv;   // undo x16 W scale
                se[j][i] += __expf(x);
                if (col == tg[j][i]) ee[j][i] = x;
            }
    }
    // blank col 1023 lives only at w==7, li==7, lrow==15 (uniform guard)
    if (w == 7) {
        float bv = bo[1023];
#pragma unroll
        for (int j = 0; j < 4; ++j)
#pragma unroll
            for (int i = 0; i < 4; ++i) {
                float x = acc[j][7][i] * 0.0625f + bv;
                if (lrow == 15) bbv[j][i] = x;
            }
    }
#pragma unroll
    for (int d = 1; d < 16; d <<= 1)
#pragma unroll
        for (int j = 0; j < 4; ++j)
#pragma unroll
            for (int i = 0; i < 4; ++i) {
                se[j][i] += __shfl_xor(se[j][i], d);
                ee[j][i] = fmaxf(ee[j][i], __shfl_xor(ee[j][i], d));
                bbv[j][i] = fmaxf(bbv[j][i], __shfl_xor(bbv[j][i], d));
            }

    // Afrag8 dead; overlay cross-wave reduction arrays [64][8].
    __syncthreads();
    float (*ps)[8] = (float (*)[8])(Afrag8);
    float (*pe)[8] = (float (*)[8])(Afrag8 + 2048);
    float (*pb)[8] = (float (*)[8])(Afrag8 + 4096);
    if (lrow == 0) {
#pragma unroll
        for (int j = 0; j < 4; ++j)
#pragma unroll
            for (int i = 0; i < 4; ++i) {
                int r = 16 * j + lhi * 4 + i;
                ps[r][w] = se[j][i]; pe[r][w] = ee[j][i]; pb[r][w] = bbv[j][i];
            }
    }
    __syncthreads();
    if (tid < 64) {
        float s = 0.f, e = NEGV, bq = NEGV;
#pragma unroll
        for (int w0 = 0; w0 < 8; ++w0) {
            s += ps[tid][w0];
            e = fmaxf(e, pe[tid][w0]);
            bq = fmaxf(bq, pb[tid][w0]);
        }
        float lse = __logf(s);
        int gid = jb * 64 + tid;
        if (gid < RTOT) {
            blank_buf[gid] = bq - lse;
            emit_buf[gid]  = e - lse;
        }
    }
}

// ---------------- RNNT DP (anti-diagonal wavefront) + combine --------------
__global__ __launch_bounds__(256)
void dp_rnnt(const float* __restrict__ blank_buf, const float* __restrict__ emit_buf,
             const int* __restrict__ frame_len, const int* __restrict__ tgt_len,
             float* __restrict__ out)
{
    __shared__ __align__(16) float sm[28416];   // pk[64][217] float2
    const int b = blockIdx.x;
    const int tid = threadIdx.x;

    float2* pk = (float2*)sm;               // [64][217]; t stored at t+8
    for (int i = tid; i < TT * U1; i += 256) {
        int t = i / U1, uu = i - t * U1;
        float bl = blank_buf[(b * TT + t) * U1 + uu];
        float em = emit_buf[(b * TT + t) * U1 + uu];
        pk[uu * 217 + t + 8] = make_float2(bl, em);
    }
    __syncthreads();
    if (tid >= 64) return;
    const int u = tid;
    const int fl = frame_len[b], tl = tgt_len[b];
    const int dh = fl - 1 + tl;             // harvest diagonal
    const bool isTL = (u == tl);
    const bool act = (u < U1);
    float A = (u == 0) ? 0.f : NEGV;
    float Asave = (dh == 0 && isTL) ? A : NEGV;
    const float2* prow = pk + u * 217;

    for (int d0 = 1; d0 <= 249; d0 += 8) {
        int tb = d0 - 1 - u;
        int tc = tb; if (tc < -8) tc = -8; if (tc > 200) tc = 200;
        float2 buf[8];
#pragma unroll
        for (int s = 0; s < 8; ++s) buf[s] = prow[tc + 8 + s];
#pragma unroll
        for (int s = 0; s < 8; ++s) {
            int d = d0 + s;
            int t_new = d - u;
            float2 be = buf[s];
            float vshare = A + be.y;
            float left = __shfl_up(vshare, 1);
            if (u == 0) left = NEGV;
            float up = (t_new >= 1) ? (A + be.x) : NEGV;
            float Anew = lae(up, left);
            bool valid = act && (t_new >= 0) && (t_new < TT);
            A = valid ? Anew : A;
            Asave = (isTL && d == dh) ? A : Asave;
        }
    }
    if (isTL && act) {
        float bl = prow[(fl - 1) + 8].x;
        atomicAdd(out, -0.25f * (Asave + bl));
    }
}

extern "C" void kernel_launch(void* const* d_in, const int* in_sizes, int n_in,
                              void* d_out, int out_size, void* d_ws, size_t ws_size,
                              hipStream_t stream)
{
    const float* x_enc   = (const float*)d_in[0];
    const float* x_dec   = (const float*)d_in[1];
    const int*   target  = (const int*)d_in[2];
    const int*   frame_l = (const int*)d_in[3];
    const int*   tgt_l   = (const int*)d_in[4];
    const float* W_ctc   = (const float*)d_in[5];
    const float* b_ctc   = (const float*)d_in[6];
    const float* W_enc   = (const float*)d_in[7];
    const float* W_pred  = (const float*)d_in[8];
    const float* b_joint = (const float*)d_in[9];
    const float* W_out   = (const float*)d_in[10];
    const float* b_out   = (const float*)d_in[11];
    float* out = (float*)d_out;

    float* wsf        = (float*)d_ws;
    float* enc_proj   = wsf;                       // 512000
    float* pred_proj  = wsf + 512000;              // 130560
    float* ctc_logits = wsf + 642560;              // 819200
    float* ctc_lse    = wsf + 1461760;             // 832
    float* blank_buf  = wsf + 1462592;             // 40832
    float* emit_buf   = wsf + 1503424;             // 40832 (+pad to 1544272)
    unsigned* FOut8 = (unsigned*)(wsf + 1544272);  // 163840 u32 (655360 B fp8)
    bf16_t* FEnc  = (bf16_t*)(wsf + 1708112);      // 327680 bf16
    bf16_t* FPred = (bf16_t*)(wsf + 1871952);      // 409600 bf16
    bf16_t* FCtc  = (bf16_t*)(wsf + 2076752);      // 524288 bf16

    pack_bf16<<<616, 256, 0, stream>>>(W_enc, W_pred, W_ctc, FEnc, FPred, FCtc, out);
    mfma_gemm3<<<427, 512, 0, stream>>>(x_enc, x_dec, FEnc, FPred, FCtc, b_ctc,
                                        enc_proj, pred_proj, ctc_logits, ctc_lse,
                                        W_out, FOut8);
    joint_gemm<<<NBLK + 4, 512, 0, stream>>>(enc_proj, pred_proj, b_joint, FOut8, b_out,
                                             target, blank_buf, emit_buf,
                                             ctc_logits, ctc_lse, frame_l, tgt_l, out);
    dp_rnnt<<<4, 256, 0, stream>>>(blank_buf, emit_buf, frame_l, tgt_l, out);
}

// Round 24
// 143.989 us; speedup vs baseline: 1.1448x; 1.0319x over previous
//
#include <hip/hip_runtime.h>
#include <hip/hip_bf16.h>

typedef __bf16 bf16_t;
typedef __attribute__((ext_vector_type(8))) __bf16 bf16x8;
typedef __attribute__((ext_vector_type(4))) float f32x4;
typedef __attribute__((ext_vector_type(8))) int i32x8;
typedef __attribute__((ext_vector_type(4))) int i32x4;

#define NEGV (-1e30f)

// Problem constants
#define BB 4
#define TT 200
#define UU 50
#define U1 51
#define VV 1024
#define DD 512
#define HH 640
#define RTOT (BB*TT*U1)      // 40800
#define NBLK 638
#define SS 101

__device__ __forceinline__ float lae(float a, float b) {
    float mx = fmaxf(a, b);
    return mx + __logf(__expf(a - mx) + __expf(b - mx));
}
__device__ __forceinline__ float lae3(float a, float b, float c) {
    float mx = fmaxf(fmaxf(a, b), c);
    return mx + __logf(__expf(a - mx) + __expf(b - mx) + __expf(c - mx));
}
// cheap tanh for the fp8 build: exp + hw-rcp (1ulp, irrelevant at fp8)
__device__ __forceinline__ float tanh_rcp(float x) {
    x = fminf(fmaxf(x, -10.f), 10.f);
    float ex = __expf(2.f * x);
    float r = __builtin_amdgcn_rcpf(ex + 1.f);
    return (ex - 1.f) * r;
}

// ---- pack W_out into fp8 e4m3 (scaled x16) for the MX K=128 MFMA.
// Layout: [nt(64)][ks(5)][l(64)][32B]; byte m of lane l holds
// k = ks*128 + (l>>4)*32 + m, col v = nt*16 + (l&15).  (A shares k-map.)
__device__ __forceinline__ void pack_out8_mx(const float* __restrict__ W, unsigned* __restrict__ Wf8,
                                             int e32)
{
    int w4   = e32 & 7;          // word within 32B
    int l    = (e32 >> 3) & 63;
    int ksnt = e32 >> 9;
    int ks   = ksnt % 5;
    int nt   = ksnt / 5;
    int v = nt * 16 + (l & 15);
    int kb = ks * 128 + ((l >> 4) << 5) + w4 * 4;
    float f[4];
#pragma unroll
    for (int t = 0; t < 4; ++t) f[t] = W[(size_t)(kb + t) * VV + v] * 16.f;
    unsigned r = __builtin_amdgcn_cvt_pk_fp8_f32(f[0], f[1], 0, false);
    r = __builtin_amdgcn_cvt_pk_fp8_f32(f[2], f[3], r, true);
    Wf8[e32] = r;
}

// Launch 1: all weight packs. Blocks 0..615: bf16 fragments (one bf16x8 per
// thread); blocks 616..1255: W_out -> fp8 MX (FOut8 first consumed by the
// JOINT launch, so packing it here is dependency-safe). Also zeroes out[0].
__global__ void pack_all(const float* __restrict__ Wenc, const float* __restrict__ Wpred,
                         const float* __restrict__ Wctc, const float* __restrict__ Wout,
                         bf16_t* __restrict__ FEnc, bf16_t* __restrict__ FPred,
                         bf16_t* __restrict__ FCtc, unsigned* __restrict__ FOut8,
                         float* __restrict__ out)
{
    if (blockIdx.x == 0 && threadIdx.x == 0) out[0] = 0.f;
    if (blockIdx.x >= 616) {
        int e32 = (blockIdx.x - 616) * 256 + threadIdx.x;   // 163840 total
        pack_out8_mx(Wout, FOut8, e32);
        return;
    }
    int f = blockIdx.x * 256 + threadIdx.x;
    const float* W; bf16_t* Wf; int K32, N;
    if (f < 40960)      { W = Wenc;  Wf = FEnc;  K32 = 16; N = 640; }
    else if (f < 92160) { f -= 40960; W = Wpred; Wf = FPred; K32 = 20; N = 640; }
    else                { f -= 92160; W = Wctc;  Wf = FCtc;  K32 = 16; N = 1024; }
    int l  = f & 63;
    int kk = (f >> 6) % K32;
    int nt = f / (64 * K32);
    int v  = nt * 16 + (l & 15);
    int kb = kk * 32 + ((l >> 4) << 2);
    bf16x8 o;
#pragma unroll
    for (int j = 0; j < 8; ++j) {
        int k = kb + (j & 3) + ((j >> 2) << 4);
        o[j] = (bf16_t)W[(size_t)k * N + v];
    }
    *(bf16x8*)&Wf[(size_t)f * 8] = o;
}

// ---------------- generic bf16 MFMA GEMM (small gemms) ---------------------
template<int K32, int L, bool LSE, int J>
__device__ void gemm_dev(const float* __restrict__ A, int M, int rowbase, int K,
                         const bf16_t* __restrict__ Wf, const float* __restrict__ bias,
                         float* __restrict__ C, float* __restrict__ lse_out, int N,
                         bf16_t* Atile, float (*ps)[8])
{
    const int tid = threadIdx.x;
#pragma unroll
    for (int it = 0; it < J * K32 / 8; ++it) {
        int fi = it * 512 + tid;
        int l = fi & 63, jk = fi >> 6;
        int j = jk / K32, kk = jk - j * K32;
        int row = rowbase + j * 16 + (l & 15);
        if (row > M - 1) row = M - 1;
        int c0 = kk * 32 + ((l >> 4) << 2);
        const float4 a0 = *(const float4*)&A[(size_t)row * K + c0];
        const float4 a1 = *(const float4*)&A[(size_t)row * K + c0 + 16];
        bf16x8 v;
        v[0] = (bf16_t)a0.x; v[1] = (bf16_t)a0.y; v[2] = (bf16_t)a0.z; v[3] = (bf16_t)a0.w;
        v[4] = (bf16_t)a1.x; v[5] = (bf16_t)a1.y; v[6] = (bf16_t)a1.z; v[7] = (bf16_t)a1.w;
        *(bf16x8*)&Atile[(size_t)fi * 8] = v;
    }
    __syncthreads();

    const int l = tid & 63, w = tid >> 6;
    const int lrow = l & 15, lhi = l >> 4;

    f32x4 acc[J][L];
#pragma unroll
    for (int j = 0; j < J; ++j)
#pragma unroll
        for (int li = 0; li < L; ++li) acc[j][li] = f32x4{0.f, 0.f, 0.f, 0.f};

    for (int kk = 0; kk < K32; ++kk) {
        bf16x8 a[J];
#pragma unroll
        for (int j = 0; j < J; ++j)
            a[j] = *(const bf16x8*)&Atile[(size_t)(((j * K32 + kk) * 64 + l) * 8)];
#pragma unroll
        for (int li = 0; li < L; ++li) {
            bf16x8 b = *(const bf16x8*)&Wf[(size_t)(((w * L + li) * K32 + kk) * 64 + l) * 8];
#pragma unroll
            for (int j = 0; j < J; ++j)
                acc[j][li] = __builtin_amdgcn_mfma_f32_16x16x32_bf16(a[j], b, acc[j][li], 0, 0, 0);
        }
    }

    float se[J][4];
    if (LSE) {
#pragma unroll
        for (int j = 0; j < J; ++j)
#pragma unroll
            for (int i = 0; i < 4; ++i) se[j][i] = 0.f;
    }
#pragma unroll
    for (int j = 0; j < J; ++j)
#pragma unroll
        for (int li = 0; li < L; ++li) {
            int col = (w * L + li) * 16 + lrow;
            float bv = bias ? bias[col] : 0.f;
#pragma unroll
            for (int i = 0; i < 4; ++i) {
                int grow = rowbase + 16 * j + lhi * 4 + i;
                float x = acc[j][li][i] + bv;
                if (grow < M) C[(size_t)grow * N + col] = x;
                if (LSE) se[j][i] += __expf(x);
            }
        }
    if (LSE) {
#pragma unroll
        for (int d = 1; d < 16; d <<= 1)
#pragma unroll
            for (int j = 0; j < J; ++j)
#pragma unroll
                for (int i = 0; i < 4; ++i) se[j][i] += __shfl_xor(se[j][i], d);
        if (lrow == 0) {
#pragma unroll
            for (int j = 0; j < J; ++j)
#pragma unroll
                for (int i = 0; i < 4; ++i) ps[16 * j + lhi * 4 + i][w] = se[j][i];
        }
        __syncthreads();
        if (tid < J * 16) {
            float s = 0.f;
#pragma unroll
            for (int w0 = 0; w0 < 8; ++w0) s += ps[tid][w0];
            int grow = rowbase + tid;
            if (grow < M) lse_out[grow] = __logf(s);
        }
    }
}

// blocks 0..49 enc(J=1), 50..56 pred(J=2), 57..106 ctc(J=1)
__global__ __launch_bounds__(512)
void mfma_gemm3(const float* __restrict__ x_enc, const float* __restrict__ x_dec,
                const bf16_t* __restrict__ FEnc, const bf16_t* __restrict__ FPred,
                const bf16_t* __restrict__ FCtc, const float* __restrict__ b_ctc,
                float* __restrict__ enc_proj, float* __restrict__ pred_proj,
                float* __restrict__ ctc_logits, float* __restrict__ ctc_lse)
{
    __shared__ bf16_t Atile[2560 * 8];   // J=2,K32=20 max: 2560 frags
    __shared__ float ps[64][8];
    int blk = blockIdx.x;
    if (blk < 50)
        gemm_dev<16, 5, false, 1>(x_enc, 800, blk * 16, 512, FEnc, nullptr, enc_proj, nullptr, 640, Atile, ps);
    else if (blk < 57)
        gemm_dev<20, 5, false, 2>(x_dec, 204, (blk - 50) * 32, 640, FPred, nullptr, pred_proj, nullptr, 640, Atile, ps);
    else
        gemm_dev<16, 8, true, 1>(x_enc, 800, (blk - 57) * 16, 512, FCtc, b_ctc, ctc_logits, ctc_lse, 1024, Atile, ps);
}

// ---------------- fused build + MX-fp8 K=128 GEMM + row-LSE + gather -------
// blocks 0..3: CTC DP (FIRST so they start in the first scheduling wave and
// hide under the joint span); blocks 4..641: joint tiles (jb = blk-4).
__global__ __launch_bounds__(512)
void joint_gemm(const float* __restrict__ enc,   // (800,640)
                const float* __restrict__ pred,  // (204,640)
                const float* __restrict__ bj,    // (640)
                const unsigned* __restrict__ Wf8,// packed fp8 (x16 scale)
                const float* __restrict__ bo,    // (1024)
                const int* __restrict__ target,  // (4,50)
                float* __restrict__ blank_buf, float* __restrict__ emit_buf,
                const float* __restrict__ ctc_logits, const float* __restrict__ ctc_lse,
                const int* __restrict__ frame_len, const int* __restrict__ tgt_len,
                float* __restrict__ out)
{
    __shared__ __align__(16) char smem[82944];       // tile 41984 | Afrag 40960
    __shared__ const float* ep[64];
    __shared__ const float* pp[64];
    const int tid = threadIdx.x;
    const int blk = blockIdx.x;

    if (blk < 4) {
        // ---- CTC DP: 2 states per lane, branchless 8-step unroll ----
        const int b = blk;
        float* lpE = (float*)smem;                   // [208]
        float* lpO = (float*)smem + 208;             // [50][209]
        for (int i = tid; i < TT; i += 512) {
            int bt = b * TT + i;
            lpE[i] = ctc_logits[(size_t)bt * VV + (VV - 1)] - ctc_lse[bt];
        }
        for (int i = tid; i < TT * UU; i += 512) {
            int t = i / UU, uu = i - t * UU;
            int bt = b * TT + t;
            lpO[uu * 209 + t] = ctc_logits[(size_t)bt * VV + target[b * UU + uu]] - ctc_lse[bt];
        }
        __syncthreads();
        if (tid >= 64) return;
        const int u = tid;
        const int fl = frame_len[b], tl = tgt_len[b];
        const bool acte = (u <= 50);
        const bool acto = (u < 50);
        bool skip = (u >= 1 && u < UU) ? (target[b * UU + u] != target[b * UU + u - 1]) : false;
        const float* orow = lpO + u * 209;
        float old_e = (u == 0) ? lpE[0] : NEGV;
        float old_o = (u == 0) ? orow[0] : NEGV;
        float Esave = (fl == 1) ? old_e : NEGV;
        float Osave = (fl == 1) ? old_o : NEGV;

        for (int t0 = 1; t0 <= 193; t0 += 8) {
            float bo8[8], be8[8];
#pragma unroll
            for (int s = 0; s < 8; ++s) { bo8[s] = orow[t0 + s]; be8[s] = lpE[t0 + s]; }
#pragma unroll
            for (int s = 0; s < 8; ++s) {
                int t = t0 + s;
                float prev_o = __shfl_up(old_o, 1);
                if (u == 0) prev_o = NEGV;
                float ne = be8[s] + lae(old_e, prev_o);
                float no = bo8[s] + lae3(old_o, old_e, skip ? prev_o : NEGV);
                old_e = acte ? ne : NEGV;
                old_o = acto ? no : NEGV;
                bool hv = (t == fl - 1) && (t < TT);
                Esave = hv ? old_e : Esave;
                Osave = hv ? old_o : Osave;
            }
        }
        float a_last = __shfl(Esave, tl);
        float a_prev = __shfl(Osave, tl - 1);
        if (u == 0) atomicAdd(out, -0.075f * lae(a_last, a_prev));
        return;
    }

    const int jb = blk - 4;               // joint row-tile index 0..637
    char* tile = smem;                    // P1 output [64][656B]
    char* Afrag8 = smem + 41984;          // fragment-order A (40960B)
    const int l = tid & 63, w = tid >> 6;
    const int lrow = l & 15, lhi = l >> 4;

    if (tid < 64) {
        int r = jb * 64 + tid; if (r > RTOT - 1) r = RTOT - 1;
        int b = r / (TT * U1); int rem = r - b * (TT * U1);
        int t = rem / U1;      int u = rem - t * U1;
        ep[tid] = enc + (size_t)(b * TT + t) * HH;
        pp[tid] = pred + (size_t)(b * U1 + u) * HH;
    }
    __syncthreads();

    // P1: row-major coalesced compute -> tile
#pragma unroll 4
    for (int it = 0; it < 20; ++it) {
        int i = it * 512 + tid;        // 0..10239
        int row = i / 160;
        int c4 = i - row * 160;
        int c0 = c4 * 4;
        const float4 e4 = *(const float4*)&ep[row][c0];
        const float4 p4 = *(const float4*)&pp[row][c0];
        const float4 q4 = *(const float4*)&bj[c0];
        float f0 = tanh_rcp(e4.x + p4.x + q4.x);
        float f1 = tanh_rcp(e4.y + p4.y + q4.y);
        float f2 = tanh_rcp(e4.z + p4.z + q4.z);
        float f3 = tanh_rcp(e4.w + p4.w + q4.w);
        unsigned r0 = __builtin_amdgcn_cvt_pk_fp8_f32(f0, f1, 0, false);
        unsigned v = __builtin_amdgcn_cvt_pk_fp8_f32(f2, f3, r0, true);
        *(unsigned*)&tile[row * 656 + c0] = v;
    }
    __syncthreads();

    // P2: direct LDS->LDS fragment reorder (no cross-barrier registers).
#pragma unroll
    for (int it = 0; it < 5; ++it) {
        int c = it * 512 + tid;        // 0..2559
        int lA = c & 63;
        int plane = c >> 6;            // 0..39
        int h = plane & 1;
        int jks = plane >> 1;
        int ks = jks % 5;
        int j = jks / 5;
        int row = j * 16 + (lA & 15);
        int kbase = ks * 128 + ((lA >> 4) << 5) + h * 16;
        uint4 v = *(const uint4*)&tile[row * 656 + kbase];
        *(uint4*)&Afrag8[(size_t)c * 16] = v;
    }
    __syncthreads();

    f32x4 acc[4][8];
#pragma unroll
    for (int j = 0; j < 4; ++j)
#pragma unroll
        for (int li = 0; li < 8; ++li) acc[j][li] = f32x4{0.f, 0.f, 0.f, 0.f};

    const char* Bp8 = (const char*)Wf8 + (size_t)(w * 8) * 10240 + (size_t)l * 32;

    const int rot = jb % 5;
    auto kstep = [&](int ks) {
        i32x8 a[4];
#pragma unroll
        for (int j = 0; j < 4; ++j) {
            i32x4 lo = *(const i32x4*)(Afrag8 + (size_t)(((j * 5 + ks) * 2 + 0) * 1024 + l * 16));
            i32x4 hi = *(const i32x4*)(Afrag8 + (size_t)(((j * 5 + ks) * 2 + 1) * 1024 + l * 16));
            a[j][0] = lo[0]; a[j][1] = lo[1]; a[j][2] = lo[2]; a[j][3] = lo[3];
            a[j][4] = hi[0]; a[j][5] = hi[1]; a[j][6] = hi[2]; a[j][7] = hi[3];
        }
#pragma unroll
        for (int li = 0; li < 8; ++li) {
            i32x8 b = *(const i32x8*)(Bp8 + (size_t)li * 10240 + (size_t)ks * 2048);
#pragma unroll
            for (int j = 0; j < 4; ++j)
                acc[j][li] = __builtin_amdgcn_mfma_scale_f32_16x16x128_f8f6f4(
                    a[j], b, acc[j][li], 0, 0,
                    0, 0x7F7F7F7F, 0, 0x7F7F7F7F);   // scales = 1.0 (e8m0 127)
        }
    };
    for (int ks0 = rot; ks0 < 5; ++ks0) kstep(ks0);
    for (int ks0 = 0; ks0 < rot; ++ks0) kstep(ks0);

    // per-thread target tokens for the 16 owned rows
    int tg[4][4];
#pragma unroll
    for (int j = 0; j < 4; ++j)
#pragma unroll
        for (int i = 0; i < 4; ++i) {
            int r = jb * 64 + 16 * j + lhi * 4 + i; if (r > RTOT - 1) r = RTOT - 1;
            int b = r / (TT * U1); int rem = r - b * (TT * U1);
            int u = rem % U1;
            tg[j][i] = (u < UU) ? target[b * UU + u] : -1;
        }

    float se[4][4], ee[4][4], bbv[4][4];
#pragma unroll
    for (int j = 0; j < 4; ++j)
#pragma unroll
        for (int i = 0; i < 4; ++i) { se[j][i] = 0.f; ee[j][i] = NEGV; bbv[j][i] = NEGV; }

#pragma unroll
    for (int li = 0; li < 8; ++li) {
        int col = (w * 8 + li) * 16 + lrow;
        float bv = bo[col];
#pragma unroll
        for (int j = 0; j < 4; ++j)
#pragma unroll
            for (int i = 0; i < 4; ++i) {
                float x = acc[j][li][i] * 0.0625f + bv;   // undo x16 W scale
                se[j][i] += __expf(x);
                if (col == tg[j][i]) ee[j][i] = x;
            }
    }
    // blank col 1023 lives only at w==7, li==7, lrow==15 (uniform guard)
    if (w == 7) {
        float bv = bo[1023];
#pragma unroll
        for (int j = 0; j < 4; ++j)
#pragma unroll
            for (int i = 0; i < 4; ++i) {
                float x = acc[j][7][i] * 0.0625f + bv;
                if (lrow == 15) bbv[j][i] = x;
            }
    }
#pragma unroll
    for (int d = 1; d < 16; d <<= 1)
#pragma unroll
        for (int j = 0; j < 4; ++j)
#pragma unroll
            for (int i = 0; i < 4; ++i) {
                se[j][i] += __shfl_xor(se[j][i], d);
                ee[j][i] = fmaxf(ee[j][i], __shfl_xor(ee[j][i], d));
                bbv[j][i] = fmaxf(bbv[j][i], __shfl_xor(bbv[j][i], d));
            }

    // Afrag8 dead; overlay cross-wave reduction arrays [64][8].
    __syncthreads();
    float (*ps)[8] = (float (*)[8])(Afrag8);
    float (*pe)[8] = (float (*)[8])(Afrag8 + 2048);
    float (*pb)[8] = (float (*)[8])(Afrag8 + 4096);
    if (lrow == 0) {
#pragma unroll
        for (int j = 0; j < 4; ++j)
#pragma unroll
            for (int i = 0; i < 4; ++i) {
                int r = 16 * j + lhi * 4 + i;
                ps[r][w] = se[j][i]; pe[r][w] = ee[j][i]; pb[r][w] = bbv[j][i];
            }
    }
    __syncthreads();
    if (tid < 64) {
        float s = 0.f, e = NEGV, bq = NEGV;
#pragma unroll
        for (int w0 = 0; w0 < 8; ++w0) {
            s += ps[tid][w0];
            e = fmaxf(e, pe[tid][w0]);
            bq = fmaxf(bq, pb[tid][w0]);
        }
        float lse = __logf(s);
        int gid = jb * 64 + tid;
        if (gid < RTOT) {
            blank_buf[gid] = bq - lse;
            emit_buf[gid]  = e - lse;
        }
    }
}

// ---------------- RNNT DP (anti-diagonal wavefront) + combine --------------
__global__ __launch_bounds__(512)
void dp_rnnt(const float* __restrict__ blank_buf, const float* __restrict__ emit_buf,
             const int* __restrict__ frame_len, const int* __restrict__ tgt_len,
             float* __restrict__ out)
{
    __shared__ __align__(16) float sm[28416];   // pk[64][217] float2
    const int b = blockIdx.x;
    const int tid = threadIdx.x;

    float2* pk = (float2*)sm;               // [64][217]; t stored at t+8
    for (int i = tid; i < TT * U1; i += 512) {
        int t = i / U1, uu = i - t * U1;
        float bl = blank_buf[(b * TT + t) * U1 + uu];
        float em = emit_buf[(b * TT + t) * U1 + uu];
        pk[uu * 217 + t + 8] = make_float2(bl, em);
    }
    __syncthreads();
    if (tid >= 64) return;
    const int u = tid;
    const int fl = frame_len[b], tl = tgt_len[b];
    const int dh = fl - 1 + tl;             // harvest diagonal
    const bool isTL = (u == tl);
    const bool act = (u < U1);
    float A = (u == 0) ? 0.f : NEGV;
    float Asave = (dh == 0 && isTL) ? A : NEGV;
    const float2* prow = pk + u * 217;

    for (int d0 = 1; d0 <= 249; d0 += 8) {
        int tb = d0 - 1 - u;
        int tc = tb; if (tc < -8) tc = -8; if (tc > 200) tc = 200;
        float2 buf[8];
#pragma unroll
        for (int s = 0; s < 8; ++s) buf[s] = prow[tc + 8 + s];
#pragma unroll
        for (int s = 0; s < 8; ++s) {
            int d = d0 + s;
            int t_new = d - u;
            float2 be = buf[s];
            float vshare = A + be.y;
            float left = __shfl_up(vshare, 1);
            if (u == 0) left = NEGV;
            float up = (t_new >= 1) ? (A + be.x) : NEGV;
            float Anew = lae(up, left);
            bool valid = act && (t_new >= 0) && (t_new < TT);
            A = valid ? Anew : A;
            Asave = (isTL && d == dh) ? A : Asave;
        }
    }
    if (isTL && act) {
        float bl = prow[(fl - 1) + 8].x;
        atomicAdd(out, -0.25f * (Asave + bl));
    }
}

extern "C" void kernel_launch(void* const* d_in, const int* in_sizes, int n_in,
                              void* d_out, int out_size, void* d_ws, size_t ws_size,
                              hipStream_t stream)
{
    const float* x_enc   = (const float*)d_in[0];
    const float* x_dec   = (const float*)d_in[1];
    const int*   target  = (const int*)d_in[2];
    const int*   frame_l = (const int*)d_in[3];
    const int*   tgt_l   = (const int*)d_in[4];
    const float* W_ctc   = (const float*)d_in[5];
    const float* b_ctc   = (const float*)d_in[6];
    const float* W_enc   = (const float*)d_in[7];
    const float* W_pred  = (const float*)d_in[8];
    const float* b_joint = (const float*)d_in[9];
    const float* W_out   = (const float*)d_in[10];
    const float* b_out   = (const float*)d_in[11];
    float* out = (float*)d_out;

    float* wsf        = (float*)d_ws;
    float* enc_proj   = wsf;                       // 512000
    float* pred_proj  = wsf + 512000;              // 130560
    float* ctc_logits = wsf + 642560;              // 819200
    float* ctc_lse    = wsf + 1461760;             // 832
    float* blank_buf  = wsf + 1462592;             // 40832
    float* emit_buf   = wsf + 1503424;             // 40832 (+pad to 1544272)
    unsigned* FOut8 = (unsigned*)(wsf + 1544272);  // 163840 u32 (655360 B fp8)
    bf16_t* FEnc  = (bf16_t*)(wsf + 1708112);      // 327680 bf16
    bf16_t* FPred = (bf16_t*)(wsf + 1871952);      // 409600 bf16
    bf16_t* FCtc  = (bf16_t*)(wsf + 2076752);      // 524288 bf16

    pack_all<<<1256, 256, 0, stream>>>(W_enc, W_pred, W_ctc, W_out,
                                       FEnc, FPred, FCtc, FOut8, out);
    mfma_gemm3<<<107, 512, 0, stream>>>(x_enc, x_dec, FEnc, FPred, FCtc, b_ctc,
                                        enc_proj, pred_proj, ctc_logits, ctc_lse);
    joint_gemm<<<NBLK + 4, 512, 0, stream>>>(enc_proj, pred_proj, b_joint, FOut8, b_out,
                                             target, blank_buf, emit_buf,
                                             ctc_logits, ctc_lse, frame_l, tgt_l, out);
    dp_rnnt<<<4, 512, 0, stream>>>(blank_buf, emit_buf, frame_l, tgt_l, out);
}

// Round 25
// 142.624 us; speedup vs baseline: 1.1557x; 1.0096x over previous
//
#include <hip/hip_runtime.h>
#include <hip/hip_bf16.h>

typedef __bf16 bf16_t;
typedef __attribute__((ext_vector_type(8))) __bf16 bf16x8;
typedef __attribute__((ext_vector_type(4))) float f32x4;
typedef __attribute__((ext_vector_type(8))) int i32x8;
typedef __attribute__((ext_vector_type(4))) int i32x4;

#define NEGV (-1e30f)

// Problem constants
#define BB 4
#define TT 200
#define UU 50
#define U1 51
#define VV 1024
#define DD 512
#define HH 640
#define RTOT (BB*TT*U1)      // 40800
#define NBLK 638
#define SS 101

__device__ __forceinline__ float lae(float a, float b) {
    float mx = fmaxf(a, b);
    return mx + __logf(__expf(a - mx) + __expf(b - mx));
}
__device__ __forceinline__ float lae3(float a, float b, float c) {
    float mx = fmaxf(fmaxf(a, b), c);
    return mx + __logf(__expf(a - mx) + __expf(b - mx) + __expf(c - mx));
}
// cheap tanh for the fp8 build: exp + hw-rcp (1ulp, irrelevant at fp8)
__device__ __forceinline__ float tanh_rcp(float x) {
    x = fminf(fmaxf(x, -10.f), 10.f);
    float ex = __expf(2.f * x);
    float r = __builtin_amdgcn_rcpf(ex + 1.f);
    return (ex - 1.f) * r;
}

// ---- pack W_out into fp8 e4m3 (scaled x16) for the MX K=128 MFMA.
// Layout: [nt(64)][ks(5)][l(64)][32B]; byte m of lane l holds
// k = ks*128 + (l>>4)*32 + m, col v = nt*16 + (l&15).  (A shares k-map.)
__device__ __forceinline__ void pack_out8_mx(const float* __restrict__ W, unsigned* __restrict__ Wf8,
                                             int e32)
{
    int w4   = e32 & 7;          // word within 32B
    int l    = (e32 >> 3) & 63;
    int ksnt = e32 >> 9;
    int ks   = ksnt % 5;
    int nt   = ksnt / 5;
    int v = nt * 16 + (l & 15);
    int kb = ks * 128 + ((l >> 4) << 5) + w4 * 4;
    float f[4];
#pragma unroll
    for (int t = 0; t < 4; ++t) f[t] = W[(size_t)(kb + t) * VV + v] * 16.f;
    unsigned r = __builtin_amdgcn_cvt_pk_fp8_f32(f[0], f[1], 0, false);
    r = __builtin_amdgcn_cvt_pk_fp8_f32(f[2], f[3], r, true);
    Wf8[e32] = r;
}

// Launch 1: all weight packs + zero ctc_sum + zero out[0].
// Blocks 0..615: bf16 fragments; blocks 616..1255: W_out -> fp8 MX.
__global__ void pack_all(const float* __restrict__ Wenc, const float* __restrict__ Wpred,
                         const float* __restrict__ Wctc, const float* __restrict__ Wout,
                         bf16_t* __restrict__ FEnc, bf16_t* __restrict__ FPred,
                         bf16_t* __restrict__ FCtc, unsigned* __restrict__ FOut8,
                         float* __restrict__ ctc_sum, float* __restrict__ out)
{
    int z = blockIdx.x * 256 + threadIdx.x;
    if (z == 0) out[0] = 0.f;
    if (z < 832) ctc_sum[z] = 0.f;
    if (blockIdx.x >= 616) {
        int e32 = (blockIdx.x - 616) * 256 + threadIdx.x;   // 163840 total
        pack_out8_mx(Wout, FOut8, e32);
        return;
    }
    int f = blockIdx.x * 256 + threadIdx.x;
    const float* W; bf16_t* Wf; int K32, N;
    if (f < 40960)      { W = Wenc;  Wf = FEnc;  K32 = 16; N = 640; }
    else if (f < 92160) { f -= 40960; W = Wpred; Wf = FPred; K32 = 20; N = 640; }
    else                { f -= 92160; W = Wctc;  Wf = FCtc;  K32 = 16; N = 1024; }
    int l  = f & 63;
    int kk = (f >> 6) % K32;
    int nt = f / (64 * K32);
    int v  = nt * 16 + (l & 15);
    int kb = kk * 32 + ((l >> 4) << 2);
    bf16x8 o;
#pragma unroll
    for (int j = 0; j < 8; ++j) {
        int k = kb + (j & 3) + ((j >> 2) << 4);
        o[j] = (bf16_t)W[(size_t)k * N + v];
    }
    *(bf16x8*)&Wf[(size_t)f * 8] = o;
}

// ---------------- generic bf16 MFMA GEMM (small gemms) ---------------------
// SUM: accumulate per-row sum(exp(x)) into sum_out via atomicAdd (no log).
// colbase: global column offset of this block's N-slice (Wf pre-offset by
// the caller to the matching fragment tile).
template<int K32, int L, bool SUM, int J>
__device__ void gemm_dev(const float* __restrict__ A, int M, int rowbase, int K,
                         const bf16_t* __restrict__ Wf, const float* __restrict__ bias,
                         float* __restrict__ C, float* __restrict__ sum_out, int N,
                         int colbase, bf16_t* Atile, float (*ps)[8])
{
    const int tid = threadIdx.x;
#pragma unroll
    for (int it = 0; it < J * K32 / 8; ++it) {
        int fi = it * 512 + tid;
        int l = fi & 63, jk = fi >> 6;
        int j = jk / K32, kk = jk - j * K32;
        int row = rowbase + j * 16 + (l & 15);
        if (row > M - 1) row = M - 1;
        int c0 = kk * 32 + ((l >> 4) << 2);
        const float4 a0 = *(const float4*)&A[(size_t)row * K + c0];
        const float4 a1 = *(const float4*)&A[(size_t)row * K + c0 + 16];
        bf16x8 v;
        v[0] = (bf16_t)a0.x; v[1] = (bf16_t)a0.y; v[2] = (bf16_t)a0.z; v[3] = (bf16_t)a0.w;
        v[4] = (bf16_t)a1.x; v[5] = (bf16_t)a1.y; v[6] = (bf16_t)a1.z; v[7] = (bf16_t)a1.w;
        *(bf16x8*)&Atile[(size_t)fi * 8] = v;
    }
    __syncthreads();

    const int l = tid & 63, w = tid >> 6;
    const int lrow = l & 15, lhi = l >> 4;

    f32x4 acc[J][L];
#pragma unroll
    for (int j = 0; j < J; ++j)
#pragma unroll
        for (int li = 0; li < L; ++li) acc[j][li] = f32x4{0.f, 0.f, 0.f, 0.f};

    for (int kk = 0; kk < K32; ++kk) {
        bf16x8 a[J];
#pragma unroll
        for (int j = 0; j < J; ++j)
            a[j] = *(const bf16x8*)&Atile[(size_t)(((j * K32 + kk) * 64 + l) * 8)];
#pragma unroll
        for (int li = 0; li < L; ++li) {
            bf16x8 b = *(const bf16x8*)&Wf[(size_t)(((w * L + li) * K32 + kk) * 64 + l) * 8];
#pragma unroll
            for (int j = 0; j < J; ++j)
                acc[j][li] = __builtin_amdgcn_mfma_f32_16x16x32_bf16(a[j], b, acc[j][li], 0, 0, 0);
        }
    }

    float se[J][4];
    if (SUM) {
#pragma unroll
        for (int j = 0; j < J; ++j)
#pragma unroll
            for (int i = 0; i < 4; ++i) se[j][i] = 0.f;
    }
#pragma unroll
    for (int j = 0; j < J; ++j)
#pragma unroll
        for (int li = 0; li < L; ++li) {
            int col = colbase + (w * L + li) * 16 + lrow;
            float bv = bias ? bias[col] : 0.f;
#pragma unroll
            for (int i = 0; i < 4; ++i) {
                int grow = rowbase + 16 * j + lhi * 4 + i;
                float x = acc[j][li][i] + bv;
                if (grow < M) C[(size_t)grow * N + col] = x;
                if (SUM) se[j][i] += __expf(x);
            }
        }
    if (SUM) {
#pragma unroll
        for (int d = 1; d < 16; d <<= 1)
#pragma unroll
            for (int j = 0; j < J; ++j)
#pragma unroll
                for (int i = 0; i < 4; ++i) se[j][i] += __shfl_xor(se[j][i], d);
        if (lrow == 0) {
#pragma unroll
            for (int j = 0; j < J; ++j)
#pragma unroll
                for (int i = 0; i < 4; ++i) ps[16 * j + lhi * 4 + i][w] = se[j][i];
        }
        __syncthreads();
        if (tid < J * 16) {
            float s = 0.f;
#pragma unroll
            for (int w0 = 0; w0 < 8; ++w0) s += ps[tid][w0];
            int grow = rowbase + tid;
            if (grow < M) atomicAdd(&sum_out[grow], s);
        }
    }
}

// blocks 0..49 enc(J=1,L=5), 50..56 pred(J=2,L=5),
// 57..156 ctc split into two 512-col halves (J=1,L=4, sum-exp partials).
__global__ __launch_bounds__(512)
void mfma_gemm3(const float* __restrict__ x_enc, const float* __restrict__ x_dec,
                const bf16_t* __restrict__ FEnc, const bf16_t* __restrict__ FPred,
                const bf16_t* __restrict__ FCtc, const float* __restrict__ b_ctc,
                float* __restrict__ enc_proj, float* __restrict__ pred_proj,
                float* __restrict__ ctc_logits, float* __restrict__ ctc_sum)
{
    __shared__ bf16_t Atile[2560 * 8];   // J=2,K32=20 max: 2560 frags
    __shared__ float ps[64][8];
    int blk = blockIdx.x;
    if (blk < 50)
        gemm_dev<16, 5, false, 1>(x_enc, 800, blk * 16, 512, FEnc, nullptr, enc_proj, nullptr, 640, 0, Atile, ps);
    else if (blk < 57)
        gemm_dev<20, 5, false, 2>(x_dec, 204, (blk - 50) * 32, 640, FPred, nullptr, pred_proj, nullptr, 640, 0, Atile, ps);
    else {
        int c = blk - 57;             // 0..99
        int h = c / 50;               // column half
        int rb = (c % 50) * 16;
        gemm_dev<16, 4, true, 1>(x_enc, 800, rb, 512, FCtc + (size_t)h * 32 * 8192, b_ctc,
                                 ctc_logits, ctc_sum, 1024, h * 512, Atile, ps);
    }
}

// ---------------- fused build + MX-fp8 K=128 GEMM + row-LSE + gather -------
// blocks 0..3: CTC DP (FIRST so they hide under the joint span);
// blocks 4..641: joint tiles (jb = blk-4).
__global__ __launch_bounds__(512)
void joint_gemm(const float* __restrict__ enc,   // (800,640)
                const float* __restrict__ pred,  // (204,640)
                const float* __restrict__ bj,    // (640)
                const unsigned* __restrict__ Wf8,// packed fp8 (x16 scale)
                const float* __restrict__ bo,    // (1024)
                const int* __restrict__ target,  // (4,50)
                float* __restrict__ blank_buf, float* __restrict__ emit_buf,
                const float* __restrict__ ctc_logits, const float* __restrict__ ctc_sum,
                const int* __restrict__ frame_len, const int* __restrict__ tgt_len,
                float* __restrict__ out)
{
    __shared__ __align__(16) char smem[82944];       // tile 41984 | Afrag 40960
    __shared__ const float* ep[64];
    __shared__ const float* pp[64];
    const int tid = threadIdx.x;
    const int blk = blockIdx.x;

    if (blk < 4) {
        // ---- CTC DP: 2 states per lane, branchless 8-step unroll ----
        const int b = blk;
        float* lpE = (float*)smem;                   // [208]
        float* lpO = (float*)smem + 208;             // [50][209]
        float* lsb = (float*)smem + 208 + 50 * 209;  // [200] row log-sums
        for (int i = tid; i < TT; i += 512)
            lsb[i] = __logf(ctc_sum[b * TT + i]);
        __syncthreads();
        for (int i = tid; i < TT; i += 512) {
            int bt = b * TT + i;
            lpE[i] = ctc_logits[(size_t)bt * VV + (VV - 1)] - lsb[i];
        }
        for (int i = tid; i < TT * UU; i += 512) {
            int t = i / UU, uu = i - t * UU;
            int bt = b * TT + t;
            lpO[uu * 209 + t] = ctc_logits[(size_t)bt * VV + target[b * UU + uu]] - lsb[t];
        }
        __syncthreads();
        if (tid >= 64) return;
        const int u = tid;
        const int fl = frame_len[b], tl = tgt_len[b];
        const bool acte = (u <= 50);
        const bool acto = (u < 50);
        bool skip = (u >= 1 && u < UU) ? (target[b * UU + u] != target[b * UU + u - 1]) : false;
        const float* orow = lpO + u * 209;
        float old_e = (u == 0) ? lpE[0] : NEGV;
        float old_o = (u == 0) ? orow[0] : NEGV;
        float Esave = (fl == 1) ? old_e : NEGV;
        float Osave = (fl == 1) ? old_o : NEGV;

        for (int t0 = 1; t0 <= 193; t0 += 8) {
            float bo8[8], be8[8];
#pragma unroll
            for (int s = 0; s < 8; ++s) { bo8[s] = orow[t0 + s]; be8[s] = lpE[t0 + s]; }
#pragma unroll
            for (int s = 0; s < 8; ++s) {
                int t = t0 + s;
                float prev_o = __shfl_up(old_o, 1);
                if (u == 0) prev_o = NEGV;
                float ne = be8[s] + lae(old_e, prev_o);
                float no = bo8[s] + lae3(old_o, old_e, skip ? prev_o : NEGV);
                old_e = acte ? ne : NEGV;
                old_o = acto ? no : NEGV;
                bool hv = (t == fl - 1) && (t < TT);
                Esave = hv ? old_e : Esave;
                Osave = hv ? old_o : Osave;
            }
        }
        float a_last = __shfl(Esave, tl);
        float a_prev = __shfl(Osave, tl - 1);
        if (u == 0) atomicAdd(out, -0.075f * lae(a_last, a_prev));
        return;
    }

    const int jb = blk - 4;               // joint row-tile index 0..637
    char* tile = smem;                    // P1 output [64][656B]
    char* Afrag8 = smem + 41984;          // fragment-order A (40960B)
    const int l = tid & 63, w = tid >> 6;
    const int lrow = l & 15, lhi = l >> 4;

    if (tid < 64) {
        int r = jb * 64 + tid; if (r > RTOT - 1) r = RTOT - 1;
        int b = r / (TT * U1); int rem = r - b * (TT * U1);
        int t = rem / U1;      int u = rem - t * U1;
        ep[tid] = enc + (size_t)(b * TT + t) * HH;
        pp[tid] = pred + (size_t)(b * U1 + u) * HH;
    }
    __syncthreads();

    // P1: row-major coalesced compute -> tile
#pragma unroll 4
    for (int it = 0; it < 20; ++it) {
        int i = it * 512 + tid;        // 0..10239
        int row = i / 160;
        int c4 = i - row * 160;
        int c0 = c4 * 4;
        const float4 e4 = *(const float4*)&ep[row][c0];
        const float4 p4 = *(const float4*)&pp[row][c0];
        const float4 q4 = *(const float4*)&bj[c0];
        float f0 = tanh_rcp(e4.x + p4.x + q4.x);
        float f1 = tanh_rcp(e4.y + p4.y + q4.y);
        float f2 = tanh_rcp(e4.z + p4.z + q4.z);
        float f3 = tanh_rcp(e4.w + p4.w + q4.w);
        unsigned r0 = __builtin_amdgcn_cvt_pk_fp8_f32(f0, f1, 0, false);
        unsigned v = __builtin_amdgcn_cvt_pk_fp8_f32(f2, f3, r0, true);
        *(unsigned*)&tile[row * 656 + c0] = v;
    }
    __syncthreads();

    // P2: direct LDS->LDS fragment reorder (no cross-barrier registers).
#pragma unroll
    for (int it = 0; it < 5; ++it) {
        int c = it * 512 + tid;        // 0..2559
        int lA = c & 63;
        int plane = c >> 6;            // 0..39
        int h = plane & 1;
        int jks = plane >> 1;
        int ks = jks % 5;
        int j = jks / 5;
        int row = j * 16 + (lA & 15);
        int kbase = ks * 128 + ((lA >> 4) << 5) + h * 16;
        uint4 v = *(const uint4*)&tile[row * 656 + kbase];
        *(uint4*)&Afrag8[(size_t)c * 16] = v;
    }
    __syncthreads();

    f32x4 acc[4][8];
#pragma unroll
    for (int j = 0; j < 4; ++j)
#pragma unroll
        for (int li = 0; li < 8; ++li) acc[j][li] = f32x4{0.f, 0.f, 0.f, 0.f};

    const char* Bp8 = (const char*)Wf8 + (size_t)(w * 8) * 10240 + (size_t)l * 32;

    const int rot = jb % 5;
    auto kstep = [&](int ks) {
        i32x8 a[4];
#pragma unroll
        for (int j = 0; j < 4; ++j) {
            i32x4 lo = *(const i32x4*)(Afrag8 + (size_t)(((j * 5 + ks) * 2 + 0) * 1024 + l * 16));
            i32x4 hi = *(const i32x4*)(Afrag8 + (size_t)(((j * 5 + ks) * 2 + 1) * 1024 + l * 16));
            a[j][0] = lo[0]; a[j][1] = lo[1]; a[j][2] = lo[2]; a[j][3] = lo[3];
            a[j][4] = hi[0]; a[j][5] = hi[1]; a[j][6] = hi[2]; a[j][7] = hi[3];
        }
#pragma unroll
        for (int li = 0; li < 8; ++li) {
            i32x8 b = *(const i32x8*)(Bp8 + (size_t)li * 10240 + (size_t)ks * 2048);
#pragma unroll
            for (int j = 0; j < 4; ++j)
                acc[j][li] = __builtin_amdgcn_mfma_scale_f32_16x16x128_f8f6f4(
                    a[j], b, acc[j][li], 0, 0,
                    0, 0x7F7F7F7F, 0, 0x7F7F7F7F);   // scales = 1.0 (e8m0 127)
        }
    };
    for (int ks0 = rot; ks0 < 5; ++ks0) kstep(ks0);
    for (int ks0 = 0; ks0 < rot; ++ks0) kstep(ks0);

    // per-thread target tokens for the 16 owned rows
    int tg[4][4];
#pragma unroll
    for (int j = 0; j < 4; ++j)
#pragma unroll
        for (int i = 0; i < 4; ++i) {
            int r = jb * 64 + 16 * j + lhi * 4 + i; if (r > RTOT - 1) r = RTOT - 1;
            int b = r / (TT * U1); int rem = r - b * (TT * U1);
            int u = rem % U1;
            tg[j][i] = (u < UU) ? target[b * UU + u] : -1;
        }

    float se[4][4], ee[4][4], bbv[4][4];
#pragma unroll
    for (int j = 0; j < 4; ++j)
#pragma unroll
        for (int i = 0; i < 4; ++i) { se[j][i] = 0.f; ee[j][i] = NEGV; bbv[j][i] = NEGV; }

#pragma unroll
    for (int li = 0; li < 8; ++li) {
        int col = (w * 8 + li) * 16 + lrow;
        float bv = bo[col];
#pragma unroll
        for (int j = 0; j < 4; ++j)
#pragma unroll
            for (int i = 0; i < 4; ++i) {
                float x = acc[j][li][i] * 0.0625f + bv;   // undo x16 W scale
                se[j][i] += __expf(x);
                if (col == tg[j][i]) ee[j][i] = x;
            }
    }
    // blank col 1023 lives only at w==7, li==7, lrow==15 (uniform guard)
    if (w == 7) {
        float bv = bo[1023];
#pragma unroll
        for (int j = 0; j < 4; ++j)
#pragma unroll
            for (int i = 0; i < 4; ++i) {
                float x = acc[j][7][i] * 0.0625f + bv;
                if (lrow == 15) bbv[j][i] = x;
            }
    }
#pragma unroll
    for (int d = 1; d < 16; d <<= 1)
#pragma unroll
        for (int j = 0; j < 4; ++j)
#pragma unroll
            for (int i = 0; i < 4; ++i) {
                se[j][i] += __shfl_xor(se[j][i], d);
                ee[j][i] = fmaxf(ee[j][i], __shfl_xor(ee[j][i], d));
                bbv[j][i] = fmaxf(bbv[j][i], __shfl_xor(bbv[j][i], d));
            }

    // Afrag8 dead; overlay cross-wave reduction arrays [64][8].
    __syncthreads();
    float (*ps)[8] = (float (*)[8])(Afrag8);
    float (*pe)[8] = (float (*)[8])(Afrag8 + 2048);
    float (*pb)[8] = (float (*)[8])(Afrag8 + 4096);
    if (lrow == 0) {
#pragma unroll
        for (int j = 0; j < 4; ++j)
#pragma unroll
            for (int i = 0; i < 4; ++i) {
                int r = 16 * j + lhi * 4 + i;
                ps[r][w] = se[j][i]; pe[r][w] = ee[j][i]; pb[r][w] = bbv[j][i];
            }
    }
    __syncthreads();
    if (tid < 64) {
        float s = 0.f, e = NEGV, bq = NEGV;
#pragma unroll
        for (int w0 = 0; w0 < 8; ++w0) {
            s += ps[tid][w0];
            e = fmaxf(e, pe[tid][w0]);
            bq = fmaxf(bq, pb[tid][w0]);
        }
        float lse = __logf(s);
        int gid = jb * 64 + tid;
        if (gid < RTOT) {
            blank_buf[gid] = bq - lse;
            emit_buf[gid]  = e - lse;
        }
    }
}

// ---------------- RNNT DP (anti-diagonal wavefront) + combine --------------
__global__ __launch_bounds__(512)
void dp_rnnt(const float* __restrict__ blank_buf, const float* __restrict__ emit_buf,
             const int* __restrict__ frame_len, const int* __restrict__ tgt_len,
             float* __restrict__ out)
{
    __shared__ __align__(16) float sm[28416];   // pk[64][217] float2
    const int b = blockIdx.x;
    const int tid = threadIdx.x;

    float2* pk = (float2*)sm;               // [64][217]; t stored at t+8
    for (int i = tid; i < TT * U1; i += 512) {
        int t = i / U1, uu = i - t * U1;
        float bl = blank_buf[(b * TT + t) * U1 + uu];
        float em = emit_buf[(b * TT + t) * U1 + uu];
        pk[uu * 217 + t + 8] = make_float2(bl, em);
    }
    __syncthreads();
    if (tid >= 64) return;
    const int u = tid;
    const int fl = frame_len[b], tl = tgt_len[b];
    const int dh = fl - 1 + tl;             // harvest diagonal
    const bool isTL = (u == tl);
    const bool act = (u < U1);
    float A = (u == 0) ? 0.f : NEGV;
    float Asave = (dh == 0 && isTL) ? A : NEGV;
    const float2* prow = pk + u * 217;

    // early exit: nothing needed past the harvest diagonal dh (block-uniform)
    for (int d0 = 1; d0 <= dh; d0 += 8) {
        int tb = d0 - 1 - u;
        int tc = tb; if (tc < -8) tc = -8; if (tc > 200) tc = 200;
        float2 buf[8];
#pragma unroll
        for (int s = 0; s < 8; ++s) buf[s] = prow[tc + 8 + s];
#pragma unroll
        for (int s = 0; s < 8; ++s) {
            int d = d0 + s;
            int t_new = d - u;
            float2 be = buf[s];
            float vshare = A + be.y;
            float left = __shfl_up(vshare, 1);
            if (u == 0) left = NEGV;
            float up = (t_new >= 1) ? (A + be.x) : NEGV;
            float Anew = lae(up, left);
            bool valid = act && (t_new >= 0) && (t_new < TT);
            A = valid ? Anew : A;
            Asave = (isTL && d == dh) ? A : Asave;
        }
    }
    if (isTL && act) {
        float bl = prow[(fl - 1) + 8].x;
        atomicAdd(out, -0.25f * (Asave + bl));
    }
}

extern "C" void kernel_launch(void* const* d_in, const int* in_sizes, int n_in,
                              void* d_out, int out_size, void* d_ws, size_t ws_size,
                              hipStream_t stream)
{
    const float* x_enc   = (const float*)d_in[0];
    const float* x_dec   = (const float*)d_in[1];
    const int*   target  = (const int*)d_in[2];
    const int*   frame_l = (const int*)d_in[3];
    const int*   tgt_l   = (const int*)d_in[4];
    const float* W_ctc   = (const float*)d_in[5];
    const float* b_ctc   = (const float*)d_in[6];
    const float* W_enc   = (const float*)d_in[7];
    const float* W_pred  = (const float*)d_in[8];
    const float* b_joint = (const float*)d_in[9];
    const float* W_out   = (const float*)d_in[10];
    const float* b_out   = (const float*)d_in[11];
    float* out = (float*)d_out;

    float* wsf        = (float*)d_ws;
    float* enc_proj   = wsf;                       // 512000
    float* pred_proj  = wsf + 512000;              // 130560
    float* ctc_logits = wsf + 642560;              // 819200
    float* ctc_sum    = wsf + 1461760;             // 832
    float* blank_buf  = wsf + 1462592;             // 40832
    float* emit_buf   = wsf + 1503424;             // 40832 (+pad to 1544272)
    unsigned* FOut8 = (unsigned*)(wsf + 1544272);  // 163840 u32 (655360 B fp8)
    bf16_t* FEnc  = (bf16_t*)(wsf + 1708112);      // 327680 bf16
    bf16_t* FPred = (bf16_t*)(wsf + 1871952);      // 409600 bf16
    bf16_t* FCtc  = (bf16_t*)(wsf + 2076752);      // 524288 bf16

    pack_all<<<1256, 256, 0, stream>>>(W_enc, W_pred, W_ctc, W_out,
                                       FEnc, FPred, FCtc, FOut8, ctc_sum, out);
    mfma_gemm3<<<157, 512, 0, stream>>>(x_enc, x_dec, FEnc, FPred, FCtc, b_ctc,
                                        enc_proj, pred_proj, ctc_logits, ctc_sum);
    joint_gemm<<<NBLK + 4, 512, 0, stream>>>(enc_proj, pred_proj, b_joint, FOut8, b_out,
                                             target, blank_buf, emit_buf,
                                             ctc_logits, ctc_sum, frame_l, tgt_l, out);
    dp_rnnt<<<4, 512, 0, stream>>>(blank_buf, emit_buf, frame_l, tgt_l, out);
}